// Round 4
// baseline (815.025 us; speedup 1.0000x reference)
//
#include <hip/hip_runtime.h>
#include <hip/hip_bf16.h>

typedef __hip_bfloat16 bf16;
typedef short bf16x8 __attribute__((ext_vector_type(8)));
typedef float f32x4 __attribute__((ext_vector_type(4)));

// B=4, T=2048, D=1024, H=16, HD=64

static __device__ __forceinline__ void glds16(const bf16* g, bf16* l) {
  __builtin_amdgcn_global_load_lds(
      (const __attribute__((address_space(1))) void*)g,
      (__attribute__((address_space(3))) void*)l, 16, 0, 0);
}

static __device__ __forceinline__ unsigned short f2b(float f) {
  return __builtin_bit_cast(unsigned short, __float2bfloat16(f));
}
static __device__ __forceinline__ float b2f(unsigned int u16bits) {
  return __builtin_bit_cast(float, u16bits << 16);
}

// ---------------- fp32 -> bf16 convert, 4 elems/thread ----------------
__global__ void k_convert(const float* __restrict__ in, unsigned short* __restrict__ out, int n4) {
  int i = blockIdx.x * 256 + threadIdx.x;
  if (i >= n4) return;
  float4 v = reinterpret_cast<const float4*>(in)[i];
  ushort4 o;
  o.x = f2b(v.x); o.y = f2b(v.y); o.z = f2b(v.z); o.w = f2b(v.w);
  reinterpret_cast<ushort4*>(out)[i] = o;
}

// ---------------- transpose R x C fp32  ->  C x R bf16 ----------------
__global__ void k_transpose(const float* __restrict__ in, bf16* __restrict__ out, int R, int C) {
  __shared__ float t[32][33];
  int c0 = blockIdx.x * 32, r0 = blockIdx.y * 32;
  int tx = threadIdx.x, ty = threadIdx.y;  // block (32,8)
  #pragma unroll
  for (int j = 0; j < 32; j += 8)
    t[ty + j][tx] = in[(size_t)(r0 + ty + j) * C + c0 + tx];
  __syncthreads();
  #pragma unroll
  for (int j = 0; j < 32; j += 8)
    out[(size_t)(c0 + ty + j) * R + r0 + tx] = __float2bfloat16(t[tx][ty + j]);
}

// ---------------- GEMM: C = A(M x 1024) * Bt(N x 1024)^T + bias ----------------
// EPI 0: scatter to Qh/Kh[b][h][t][d], Vt[b][h][d][t] (bf16, +b_qkv)
// EPI 1: Out fp32 [m][1024] (+b_fc)
template<int EPI>
__global__ __launch_bounds__(256, 2)
void k_gemm(const bf16* __restrict__ A, const bf16* __restrict__ Bt,
            const float* __restrict__ bias,
            bf16* __restrict__ Qh, bf16* __restrict__ Kh, bf16* __restrict__ Vt,
            float* __restrict__ Out)
{
  constexpr int K = 1024;
  __shared__ bf16 sA[128 * 32];
  __shared__ bf16 sB[128 * 32];
  const int tid = threadIdx.x;
  const int wv = tid >> 6, lane = tid & 63;
  const int wr = wv >> 1, wc = wv & 1;
  const int l4 = lane >> 4, l15 = lane & 15;

  // XCD-aware bijective swizzle (nwg % 8 == 0 for both grids: 1536, 512)
  const int nbx = gridDim.x;
  const int nwg = nbx * gridDim.y;
  const int flat = blockIdx.y * nbx + blockIdx.x;
  const int cpx = nwg >> 3;
  const int swz = (flat & 7) * cpx + (flat >> 3);
  const int bx = swz % nbx;
  const int by = swz / nbx;

  const int srow = lane >> 2;         // 0..15
  const int scol = (lane & 3) * 8;    // element offset 0,8,16,24
  const bf16* gA0 = A  + (size_t)(by * 128 + wv * 16 + srow) * K + scol;
  const bf16* gB0 = Bt + (size_t)(bx * 128 + wv * 16 + srow) * K + scol;
  bf16* lA0 = sA + wv * 16 * 32;      // wave-uniform LDS base; HW adds lane*16B
  bf16* lB0 = sB + wv * 16 * 32;

  f32x4 acc[4][4];
  #pragma unroll
  for (int i = 0; i < 4; ++i)
    #pragma unroll
    for (int j = 0; j < 4; ++j) acc[i][j] = f32x4{0.f, 0.f, 0.f, 0.f};

  for (int kb = 0; kb < K; kb += 32) {
    glds16(gA0 + kb,                   lA0);
    glds16(gA0 + kb + (size_t)64 * K,  lA0 + 64 * 32);
    glds16(gB0 + kb,                   lB0);
    glds16(gB0 + kb + (size_t)64 * K,  lB0 + 64 * 32);
    __syncthreads();
    bf16x8 af[4], bfr[4];
    #pragma unroll
    for (int i = 0; i < 4; ++i)
      af[i] = *reinterpret_cast<const bf16x8*>(sA + (wr * 64 + i * 16 + l15) * 32 + l4 * 8);
    #pragma unroll
    for (int j = 0; j < 4; ++j)
      bfr[j] = *reinterpret_cast<const bf16x8*>(sB + (wc * 64 + j * 16 + l15) * 32 + l4 * 8);
    #pragma unroll
    for (int i = 0; i < 4; ++i)
      #pragma unroll
      for (int j = 0; j < 4; ++j)
        acc[i][j] = __builtin_amdgcn_mfma_f32_16x16x32_bf16(af[i], bfr[j], acc[i][j], 0, 0, 0);
    __syncthreads();
  }

  if (EPI == 0) {
    #pragma unroll
    for (int j = 0; j < 4; ++j) {
      const int n = bx * 128 + wc * 64 + j * 16 + l15;
      const float bj = bias[n];
      const int s = n >> 10;
      const int hh = (n >> 6) & 15;
      const int d = n & 63;
      #pragma unroll
      for (int i = 0; i < 4; ++i) {
        #pragma unroll
        for (int r = 0; r < 4; ++r) {
          const int m = by * 128 + wr * 64 + i * 16 + l4 * 4 + r;
          const int bb = m >> 11, t = m & 2047;
          const bf16 o = __float2bfloat16(acc[i][j][r] + bj);
          if (s == 0)      Qh[((size_t)((bb * 16 + hh) * 2048 + t)) * 64 + d] = o;
          else if (s == 1) Kh[((size_t)((bb * 16 + hh) * 2048 + t)) * 64 + d] = o;
          else             Vt[((size_t)((bb * 16 + hh) * 64 + d)) * 2048 + t] = o;
        }
      }
    }
  } else {
    #pragma unroll
    for (int j = 0; j < 4; ++j) {
      const int n = bx * 128 + wc * 64 + j * 16 + l15;
      const float bj = bias[n];
      #pragma unroll
      for (int i = 0; i < 4; ++i)
        #pragma unroll
        for (int r = 0; r < 4; ++r) {
          const int m = by * 128 + wr * 64 + i * 16 + l4 * 4 + r;
          Out[(size_t)m * 1024 + n] = acc[i][j][r] + bj;
        }
    }
  }
}

// ---------------- flash attention (causal), head-major inputs ----------------
// 1-D grid of 2048 blocks, 256 threads = 4 waves.
// Block handles q-tile pair (g, 63-g); each tile's kt range is split even/odd
// between 2 waves (online softmax per wave), partials merged through LDS.
// bid->(b,h) mapping pins all 32 blocks of one head to one XCD (bid&7).
// Softmax internals are the round-2-proven code (natural exp, shuffle sums).
__global__ __launch_bounds__(256, 6)
void k_attn(const bf16* __restrict__ Qh, const bf16* __restrict__ Kh,
            const bf16* __restrict__ Vt, bf16* __restrict__ Ao)
{
  __shared__ unsigned int smem[4608];   // 18432 B: 4 P-tiles (32x72 bf16), aliased by 2 combine regions (2x8KB)
  const int tid = threadIdx.x;
  const int wv = tid >> 6, lane = tid & 63;
  const int l4 = lane >> 4, l15 = lane & 15;

  const int bid = blockIdx.x;
  const int xcd = bid & 7;
  const int idx = bid >> 3;            // 0..255
  const int g   = idx & 31;
  const int grp = idx >> 5;            // 0..7
  const int bh  = grp * 8 + xcd;       // all g-blocks of a head share an XCD
  const int b = bh >> 4, h = bh & 15;

  const int role = (wv + bid) & 3;     // rotate roles across SIMDs
  const int qi = (role < 2) ? g : (63 - g);
  const int parity = role & 1;
  const int qbase = qi * 32;

  const bf16* Qp = Qh + (size_t)bh * 2048 * 64;
  const bf16* Kp = Kh + (size_t)bh * 2048 * 64;
  const bf16* Vp = Vt + (size_t)bh * 64 * 2048;
  bf16* Pw = (bf16*)smem + wv * (32 * 72);

  bf16x8 qa[2][2];
  #pragma unroll
  for (int i = 0; i < 2; ++i)
    #pragma unroll
    for (int kh = 0; kh < 2; ++kh)
      qa[i][kh] = *reinterpret_cast<const bf16x8*>(
          Qp + (size_t)(qbase + i * 16 + l15) * 64 + kh * 32 + l4 * 8);

  f32x4 o[2][4];
  float mr[2][4], lr[2][4];
  #pragma unroll
  for (int i = 0; i < 2; ++i) {
    #pragma unroll
    for (int jd = 0; jd < 4; ++jd) o[i][jd] = f32x4{0.f, 0.f, 0.f, 0.f};
    #pragma unroll
    for (int r = 0; r < 4; ++r) { mr[i][r] = -1e30f; lr[i][r] = 0.f; }
  }

  const int ktmax = (qbase + 31) >> 6;
  for (int kt = parity; kt <= ktmax; kt += 2) {
    const bool full = (kt * 64 + 63) <= qbase;
    bf16x8 kbf[4][2];
    #pragma unroll
    for (int j = 0; j < 4; ++j)
      #pragma unroll
      for (int kh = 0; kh < 2; ++kh)
        kbf[j][kh] = *reinterpret_cast<const bf16x8*>(
            Kp + (size_t)(kt * 64 + j * 16 + l15) * 64 + kh * 32 + l4 * 8);
    // V loads issued early: latency hides under QK + softmax
    bf16x8 vbf[4][2];
    #pragma unroll
    for (int jd = 0; jd < 4; ++jd)
      #pragma unroll
      for (int kh = 0; kh < 2; ++kh)
        vbf[jd][kh] = *reinterpret_cast<const bf16x8*>(
            Vp + (size_t)(jd * 16 + l15) * 2048 + kt * 64 + kh * 32 + l4 * 8);

    f32x4 s[2][4];
    #pragma unroll
    for (int i = 0; i < 2; ++i)
      #pragma unroll
      for (int j = 0; j < 4; ++j) s[i][j] = f32x4{0.f, 0.f, 0.f, 0.f};
    #pragma unroll
    for (int i = 0; i < 2; ++i)
      #pragma unroll
      for (int j = 0; j < 4; ++j)
        #pragma unroll
        for (int kh = 0; kh < 2; ++kh)
          s[i][j] = __builtin_amdgcn_mfma_f32_16x16x32_bf16(qa[i][kh], kbf[j][kh], s[i][j], 0, 0, 0);

    // scale + causal mask (C-layout: row=(lane>>4)*4+r, col=lane&15)
    #pragma unroll
    for (int i = 0; i < 2; ++i)
      #pragma unroll
      for (int j = 0; j < 4; ++j)
        #pragma unroll
        for (int r = 0; r < 4; ++r) {
          float v = s[i][j][r] * 0.125f;
          if (!full) {
            const int q = qbase + i * 16 + l4 * 4 + r;
            const int kk = kt * 64 + j * 16 + l15;
            if (kk > q) v = -1e30f;
          }
          s[i][j][r] = v;
        }

    // online softmax per row (rows live in 16-lane groups) -- round-2-proven
    #pragma unroll
    for (int i = 0; i < 2; ++i)
      #pragma unroll
      for (int r = 0; r < 4; ++r) {
        float mx = fmaxf(fmaxf(s[i][0][r], s[i][1][r]), fmaxf(s[i][2][r], s[i][3][r]));
        #pragma unroll
        for (int dd = 1; dd < 16; dd <<= 1) mx = fmaxf(mx, __shfl_xor(mx, dd, 16));
        const float mn = fmaxf(mr[i][r], mx);
        const float al = __expf(mr[i][r] - mn);
        mr[i][r] = mn;
        float ps = 0.f;
        #pragma unroll
        for (int j = 0; j < 4; ++j) {
          const float p = __expf(s[i][j][r] - mn);
          ps += p;
          Pw[(i * 16 + l4 * 4 + r) * 72 + j * 16 + l15] = __float2bfloat16(p);
        }
        #pragma unroll
        for (int dd = 1; dd < 16; dd <<= 1) ps += __shfl_xor(ps, dd, 16);
        lr[i][r] = lr[i][r] * al + ps;
        #pragma unroll
        for (int jd = 0; jd < 4; ++jd) o[i][jd][r] *= al;
      }

    // PV: A-frags from P LDS, B-frags from transposed V (contiguous 16B)
    bf16x8 pa[2][2];
    #pragma unroll
    for (int i = 0; i < 2; ++i)
      #pragma unroll
      for (int kh = 0; kh < 2; ++kh)
        pa[i][kh] = *reinterpret_cast<const bf16x8*>(Pw + (i * 16 + l15) * 72 + kh * 32 + l4 * 8);
    #pragma unroll
    for (int i = 0; i < 2; ++i)
      #pragma unroll
      for (int jd = 0; jd < 4; ++jd)
        #pragma unroll
        for (int kh = 0; kh < 2; ++kh)
          o[i][jd] = __builtin_amdgcn_mfma_f32_16x16x32_bf16(pa[i][kh], vbf[jd][kh], o[i][jd], 0, 0, 0);
  }

  // ---- merge even/odd partials through LDS (aliases dead P buffers) ----
  __syncthreads();
  unsigned int* reg0 = smem;          // 2048 u32 = 8 KB
  unsigned int* reg1 = smem + 2048;
  if (parity == 1) {                  // writers: roles 1 (tile g) and 3 (tile 63-g)
    unsigned int* p = ((role == 1) ? reg0 : reg1) + lane * 32;
    #pragma unroll
    for (int i = 0; i < 2; ++i)
      #pragma unroll
      for (int r = 0; r < 4; ++r) {
        p[i * 4 + r]     = __builtin_bit_cast(unsigned int, mr[i][r]);
        p[8 + i * 4 + r] = __builtin_bit_cast(unsigned int, lr[i][r]);
      }
    #pragma unroll
    for (int i = 0; i < 2; ++i)
      #pragma unroll
      for (int jd = 0; jd < 4; ++jd)
        #pragma unroll
        for (int rp = 0; rp < 2; ++rp) {
          unsigned int lo = f2b(o[i][jd][2 * rp]);
          unsigned int hi = f2b(o[i][jd][2 * rp + 1]);
          p[16 + (i * 4 + jd) * 2 + rp] = lo | (hi << 16);
        }
  }
  __syncthreads();
  if (parity == 0) {                  // readers: roles 0 and 2
    const unsigned int* p = ((role == 0) ? reg0 : reg1) + lane * 32;
    #pragma unroll
    for (int i = 0; i < 2; ++i)
      #pragma unroll
      for (int r = 0; r < 4; ++r) {
        const float m1 = __builtin_bit_cast(float, p[i * 4 + r]);
        const float l1 = __builtin_bit_cast(float, p[8 + i * 4 + r]);
        const float mm = fmaxf(mr[i][r], m1);
        const float a0 = __expf(mr[i][r] - mm);
        const float a1 = __expf(m1 - mm);
        const float inv = 1.f / (lr[i][r] * a0 + l1 * a1);
        const int q = qbase + i * 16 + l4 * 4 + r;
        #pragma unroll
        for (int jd = 0; jd < 4; ++jd) {
          const unsigned int u = p[16 + (i * 4 + jd) * 2 + (r >> 1)];
          const float o1 = b2f((r & 1) ? (u >> 16) : (u & 0xffffu));
          const float val = (o[i][jd][r] * a0 + o1 * a1) * inv;
          Ao[(size_t)(b * 2048 + q) * 1024 + h * 64 + jd * 16 + l15] = __float2bfloat16(val);
        }
      }
  }
}

extern "C" void kernel_launch(void* const* d_in, const int* in_sizes, int n_in,
                              void* d_out, int out_size, void* d_ws, size_t ws_size,
                              hipStream_t stream)
{
  const float* x     = (const float*)d_in[0];
  const float* W_qkv = (const float*)d_in[1];
  const float* b_qkv = (const float*)d_in[2];
  const float* W_fc  = (const float*)d_in[3];
  const float* b_fc  = (const float*)d_in[4];
  float* out = (float*)d_out;

  char* ws = (char*)d_ws;
  bf16* x_bf = (bf16*)ws;  ws += (size_t)8192 * 1024 * 2;            // 16 MB
  bf16* Wqt  = (bf16*)ws;  ws += (size_t)3072 * 1024 * 2;            //  6 MB
  bf16* Wft  = (bf16*)ws;  ws += (size_t)1024 * 1024 * 2;            //  2 MB
  bf16* Qh   = (bf16*)ws;  ws += (size_t)4 * 16 * 2048 * 64 * 2;     // 16 MB
  bf16* Kh   = (bf16*)ws;  ws += (size_t)4 * 16 * 2048 * 64 * 2;     // 16 MB
  bf16* Vt   = (bf16*)ws;  ws += (size_t)4 * 16 * 64 * 2048 * 2;     // 16 MB
  bf16* Ao   = (bf16*)ws;  ws += (size_t)8192 * 1024 * 2;            // 16 MB  (total 88 MB)

  k_convert<<<8192, 256, 0, stream>>>(x, (unsigned short*)x_bf, 8192 * 1024 / 4);
  k_transpose<<<dim3(3072 / 32, 1024 / 32), dim3(32, 8), 0, stream>>>(W_qkv, Wqt, 1024, 3072);
  k_transpose<<<dim3(1024 / 32, 1024 / 32), dim3(32, 8), 0, stream>>>(W_fc, Wft, 1024, 1024);
  k_gemm<0><<<dim3(24, 64), 256, 0, stream>>>(x_bf, Wqt, b_qkv, Qh, Kh, Vt, nullptr);
  k_attn<<<2048, 256, 0, stream>>>(Qh, Kh, Vt, Ao);
  k_gemm<1><<<dim3(8, 64), 256, 0, stream>>>(Ao, Wft, b_fc, nullptr, nullptr, nullptr, out);
}

// Round 5
// 390.508 us; speedup vs baseline: 2.0871x; 2.0871x over previous
//
#include <hip/hip_runtime.h>
#include <hip/hip_bf16.h>

typedef __hip_bfloat16 bf16;
typedef short bf16x8 __attribute__((ext_vector_type(8)));
typedef float f32x4 __attribute__((ext_vector_type(4)));

// B=4, T=2048, D=1024, H=16, HD=64

static __device__ __forceinline__ void glds16(const bf16* g, bf16* l) {
  __builtin_amdgcn_global_load_lds(
      (const __attribute__((address_space(1))) void*)g,
      (__attribute__((address_space(3))) void*)l, 16, 0, 0);
}

static __device__ __forceinline__ unsigned short f2b(float f) {
  return __builtin_bit_cast(unsigned short, __float2bfloat16(f));
}
static __device__ __forceinline__ float b2f(unsigned int u16bits) {
  return __builtin_bit_cast(float, u16bits << 16);
}

// ---------------- fp32 -> bf16 convert, 4 elems/thread ----------------
__global__ void k_convert(const float* __restrict__ in, unsigned short* __restrict__ out, int n4) {
  int i = blockIdx.x * 256 + threadIdx.x;
  if (i >= n4) return;
  float4 v = reinterpret_cast<const float4*>(in)[i];
  ushort4 o;
  o.x = f2b(v.x); o.y = f2b(v.y); o.z = f2b(v.z); o.w = f2b(v.w);
  reinterpret_cast<ushort4*>(out)[i] = o;
}

// ---------------- transpose R x C fp32  ->  C x R bf16 ----------------
__global__ void k_transpose(const float* __restrict__ in, bf16* __restrict__ out, int R, int C) {
  __shared__ float t[32][33];
  int c0 = blockIdx.x * 32, r0 = blockIdx.y * 32;
  int tx = threadIdx.x, ty = threadIdx.y;  // block (32,8)
  #pragma unroll
  for (int j = 0; j < 32; j += 8)
    t[ty + j][tx] = in[(size_t)(r0 + ty + j) * C + c0 + tx];
  __syncthreads();
  #pragma unroll
  for (int j = 0; j < 32; j += 8)
    out[(size_t)(c0 + ty + j) * R + r0 + tx] = __float2bfloat16(t[tx][ty + j]);
}

// ---------------- GEMM: C = A(M x 1024) * Bt(N x 1024)^T + bias ----------------
// EPI 0: scatter to Qh/Kh[b][h][t][d], Vt[b][h][d][t] (bf16, +b_qkv)
// EPI 1: Out fp32 [m][1024] (+b_fc)
template<int EPI>
__global__ __launch_bounds__(256, 2)
void k_gemm(const bf16* __restrict__ A, const bf16* __restrict__ Bt,
            const float* __restrict__ bias,
            bf16* __restrict__ Qh, bf16* __restrict__ Kh, bf16* __restrict__ Vt,
            float* __restrict__ Out)
{
  constexpr int K = 1024;
  __shared__ bf16 sA[128 * 32];
  __shared__ bf16 sB[128 * 32];
  const int tid = threadIdx.x;
  const int wv = tid >> 6, lane = tid & 63;
  const int wr = wv >> 1, wc = wv & 1;
  const int l4 = lane >> 4, l15 = lane & 15;

  // XCD-aware bijective swizzle (nwg % 8 == 0 for both grids: 1536, 512)
  const int nbx = gridDim.x;
  const int nwg = nbx * gridDim.y;
  const int flat = blockIdx.y * nbx + blockIdx.x;
  const int cpx = nwg >> 3;
  const int swz = (flat & 7) * cpx + (flat >> 3);
  const int bx = swz % nbx;
  const int by = swz / nbx;

  const int srow = lane >> 2;         // 0..15
  const int scol = (lane & 3) * 8;    // element offset 0,8,16,24
  const bf16* gA0 = A  + (size_t)(by * 128 + wv * 16 + srow) * K + scol;
  const bf16* gB0 = Bt + (size_t)(bx * 128 + wv * 16 + srow) * K + scol;
  bf16* lA0 = sA + wv * 16 * 32;      // wave-uniform LDS base; HW adds lane*16B
  bf16* lB0 = sB + wv * 16 * 32;

  f32x4 acc[4][4];
  #pragma unroll
  for (int i = 0; i < 4; ++i)
    #pragma unroll
    for (int j = 0; j < 4; ++j) acc[i][j] = f32x4{0.f, 0.f, 0.f, 0.f};

  for (int kb = 0; kb < K; kb += 32) {
    glds16(gA0 + kb,                   lA0);
    glds16(gA0 + kb + (size_t)64 * K,  lA0 + 64 * 32);
    glds16(gB0 + kb,                   lB0);
    glds16(gB0 + kb + (size_t)64 * K,  lB0 + 64 * 32);
    __syncthreads();
    bf16x8 af[4], bfr[4];
    #pragma unroll
    for (int i = 0; i < 4; ++i)
      af[i] = *reinterpret_cast<const bf16x8*>(sA + (wr * 64 + i * 16 + l15) * 32 + l4 * 8);
    #pragma unroll
    for (int j = 0; j < 4; ++j)
      bfr[j] = *reinterpret_cast<const bf16x8*>(sB + (wc * 64 + j * 16 + l15) * 32 + l4 * 8);
    #pragma unroll
    for (int i = 0; i < 4; ++i)
      #pragma unroll
      for (int j = 0; j < 4; ++j)
        acc[i][j] = __builtin_amdgcn_mfma_f32_16x16x32_bf16(af[i], bfr[j], acc[i][j], 0, 0, 0);
    __syncthreads();
  }

  if (EPI == 0) {
    #pragma unroll
    for (int j = 0; j < 4; ++j) {
      const int n = bx * 128 + wc * 64 + j * 16 + l15;
      const float bj = bias[n];
      const int s = n >> 10;
      const int hh = (n >> 6) & 15;
      const int d = n & 63;
      #pragma unroll
      for (int i = 0; i < 4; ++i) {
        #pragma unroll
        for (int r = 0; r < 4; ++r) {
          const int m = by * 128 + wr * 64 + i * 16 + l4 * 4 + r;
          const int bb = m >> 11, t = m & 2047;
          const bf16 o = __float2bfloat16(acc[i][j][r] + bj);
          if (s == 0)      Qh[((size_t)((bb * 16 + hh) * 2048 + t)) * 64 + d] = o;
          else if (s == 1) Kh[((size_t)((bb * 16 + hh) * 2048 + t)) * 64 + d] = o;
          else             Vt[((size_t)((bb * 16 + hh) * 64 + d)) * 2048 + t] = o;
        }
      }
    }
  } else {
    #pragma unroll
    for (int j = 0; j < 4; ++j) {
      const int n = bx * 128 + wc * 64 + j * 16 + l15;
      const float bj = bias[n];
      #pragma unroll
      for (int i = 0; i < 4; ++i)
        #pragma unroll
        for (int r = 0; r < 4; ++r) {
          const int m = by * 128 + wr * 64 + i * 16 + l4 * 4 + r;
          Out[(size_t)m * 1024 + n] = acc[i][j][r] + bj;
        }
    }
  }
}

// ---------------- flash attention (causal), head-major inputs ----------------
// 1-D grid of 2048 blocks, 256 threads = 4 waves.
// Block handles q-tile pair (g, 63-g); each tile's kt range is split even/odd
// between 2 waves (online softmax per wave), partials merged through LDS.
// bid->(b,h) mapping pins all 32 blocks of one head to one XCD (bid&7).
// launch_bounds(256,4): (256,6) capped regs at ~85/wave -> massive scratch
// spill (VGPR_Count=40, 1.6 GB scratch writes, 690 us). V loads kept AFTER
// softmax to bound live fragment state (R1-proven: VGPR=72, zero spill).
__global__ __launch_bounds__(256, 4)
void k_attn(const bf16* __restrict__ Qh, const bf16* __restrict__ Kh,
            const bf16* __restrict__ Vt, bf16* __restrict__ Ao)
{
  __shared__ unsigned int smem[4608];   // 18432 B: 4 P-tiles (32x72 bf16), aliased by 2 combine regions (2x8KB)
  const int tid = threadIdx.x;
  const int wv = tid >> 6, lane = tid & 63;
  const int l4 = lane >> 4, l15 = lane & 15;

  const int bid = blockIdx.x;
  const int xcd = bid & 7;
  const int idx = bid >> 3;            // 0..255
  const int g   = idx & 31;
  const int grp = idx >> 5;            // 0..7
  const int bh  = grp * 8 + xcd;       // all g-blocks of a head share an XCD
  const int b = bh >> 4, h = bh & 15;

  const int role = (wv + bid) & 3;     // rotate roles across SIMDs
  const int qi = (role < 2) ? g : (63 - g);
  const int parity = role & 1;
  const int qbase = qi * 32;

  const bf16* Qp = Qh + (size_t)bh * 2048 * 64;
  const bf16* Kp = Kh + (size_t)bh * 2048 * 64;
  const bf16* Vp = Vt + (size_t)bh * 64 * 2048;
  bf16* Pw = (bf16*)smem + wv * (32 * 72);

  bf16x8 qa[2][2];
  #pragma unroll
  for (int i = 0; i < 2; ++i)
    #pragma unroll
    for (int kh = 0; kh < 2; ++kh)
      qa[i][kh] = *reinterpret_cast<const bf16x8*>(
          Qp + (size_t)(qbase + i * 16 + l15) * 64 + kh * 32 + l4 * 8);

  f32x4 o[2][4];
  float mr[2][4], lr[2][4];
  #pragma unroll
  for (int i = 0; i < 2; ++i) {
    #pragma unroll
    for (int jd = 0; jd < 4; ++jd) o[i][jd] = f32x4{0.f, 0.f, 0.f, 0.f};
    #pragma unroll
    for (int r = 0; r < 4; ++r) { mr[i][r] = -1e30f; lr[i][r] = 0.f; }
  }

  const int ktmax = (qbase + 31) >> 6;
  for (int kt = parity; kt <= ktmax; kt += 2) {
    const bool full = (kt * 64 + 63) <= qbase;
    bf16x8 kbf[4][2];
    #pragma unroll
    for (int j = 0; j < 4; ++j)
      #pragma unroll
      for (int kh = 0; kh < 2; ++kh)
        kbf[j][kh] = *reinterpret_cast<const bf16x8*>(
            Kp + (size_t)(kt * 64 + j * 16 + l15) * 64 + kh * 32 + l4 * 8);

    f32x4 s[2][4];
    #pragma unroll
    for (int i = 0; i < 2; ++i)
      #pragma unroll
      for (int j = 0; j < 4; ++j) s[i][j] = f32x4{0.f, 0.f, 0.f, 0.f};
    #pragma unroll
    for (int i = 0; i < 2; ++i)
      #pragma unroll
      for (int j = 0; j < 4; ++j)
        #pragma unroll
        for (int kh = 0; kh < 2; ++kh)
          s[i][j] = __builtin_amdgcn_mfma_f32_16x16x32_bf16(qa[i][kh], kbf[j][kh], s[i][j], 0, 0, 0);

    // scale + causal mask (C-layout: row=(lane>>4)*4+r, col=lane&15)
    #pragma unroll
    for (int i = 0; i < 2; ++i)
      #pragma unroll
      for (int j = 0; j < 4; ++j)
        #pragma unroll
        for (int r = 0; r < 4; ++r) {
          float v = s[i][j][r] * 0.125f;
          if (!full) {
            const int q = qbase + i * 16 + l4 * 4 + r;
            const int kk = kt * 64 + j * 16 + l15;
            if (kk > q) v = -1e30f;
          }
          s[i][j][r] = v;
        }

    // online softmax per row (rows live in 16-lane groups) -- round-2-proven
    #pragma unroll
    for (int i = 0; i < 2; ++i)
      #pragma unroll
      for (int r = 0; r < 4; ++r) {
        float mx = fmaxf(fmaxf(s[i][0][r], s[i][1][r]), fmaxf(s[i][2][r], s[i][3][r]));
        #pragma unroll
        for (int dd = 1; dd < 16; dd <<= 1) mx = fmaxf(mx, __shfl_xor(mx, dd, 16));
        const float mn = fmaxf(mr[i][r], mx);
        const float al = __expf(mr[i][r] - mn);
        mr[i][r] = mn;
        float ps = 0.f;
        #pragma unroll
        for (int j = 0; j < 4; ++j) {
          const float p = __expf(s[i][j][r] - mn);
          ps += p;
          Pw[(i * 16 + l4 * 4 + r) * 72 + j * 16 + l15] = __float2bfloat16(p);
        }
        #pragma unroll
        for (int dd = 1; dd < 16; dd <<= 1) ps += __shfl_xor(ps, dd, 16);
        lr[i][r] = lr[i][r] * al + ps;
        #pragma unroll
        for (int jd = 0; jd < 4; ++jd) o[i][jd][r] *= al;
      }

    // PV: A-frags from P LDS, B-frags from transposed V (contiguous 16B).
    // V loaded here (not earlier) to keep live VGPR state under the cap.
    bf16x8 vbf[4][2];
    #pragma unroll
    for (int jd = 0; jd < 4; ++jd)
      #pragma unroll
      for (int kh = 0; kh < 2; ++kh)
        vbf[jd][kh] = *reinterpret_cast<const bf16x8*>(
            Vp + (size_t)(jd * 16 + l15) * 2048 + kt * 64 + kh * 32 + l4 * 8);
    bf16x8 pa[2][2];
    #pragma unroll
    for (int i = 0; i < 2; ++i)
      #pragma unroll
      for (int kh = 0; kh < 2; ++kh)
        pa[i][kh] = *reinterpret_cast<const bf16x8*>(Pw + (i * 16 + l15) * 72 + kh * 32 + l4 * 8);
    #pragma unroll
    for (int i = 0; i < 2; ++i)
      #pragma unroll
      for (int jd = 0; jd < 4; ++jd)
        #pragma unroll
        for (int kh = 0; kh < 2; ++kh)
          o[i][jd] = __builtin_amdgcn_mfma_f32_16x16x32_bf16(pa[i][kh], vbf[jd][kh], o[i][jd], 0, 0, 0);
  }

  // ---- merge even/odd partials through LDS (aliases dead P buffers) ----
  __syncthreads();
  unsigned int* reg0 = smem;          // 2048 u32 = 8 KB
  unsigned int* reg1 = smem + 2048;
  if (parity == 1) {                  // writers: roles 1 (tile g) and 3 (tile 63-g)
    unsigned int* p = ((role == 1) ? reg0 : reg1) + lane * 32;
    #pragma unroll
    for (int i = 0; i < 2; ++i)
      #pragma unroll
      for (int r = 0; r < 4; ++r) {
        p[i * 4 + r]     = __builtin_bit_cast(unsigned int, mr[i][r]);
        p[8 + i * 4 + r] = __builtin_bit_cast(unsigned int, lr[i][r]);
      }
    #pragma unroll
    for (int i = 0; i < 2; ++i)
      #pragma unroll
      for (int jd = 0; jd < 4; ++jd)
        #pragma unroll
        for (int rp = 0; rp < 2; ++rp) {
          unsigned int lo = f2b(o[i][jd][2 * rp]);
          unsigned int hi = f2b(o[i][jd][2 * rp + 1]);
          p[16 + (i * 4 + jd) * 2 + rp] = lo | (hi << 16);
        }
  }
  __syncthreads();
  if (parity == 0) {                  // readers: roles 0 and 2
    const unsigned int* p = ((role == 0) ? reg0 : reg1) + lane * 32;
    #pragma unroll
    for (int i = 0; i < 2; ++i)
      #pragma unroll
      for (int r = 0; r < 4; ++r) {
        const float m1 = __builtin_bit_cast(float, p[i * 4 + r]);
        const float l1 = __builtin_bit_cast(float, p[8 + i * 4 + r]);
        const float mm = fmaxf(mr[i][r], m1);
        const float a0 = __expf(mr[i][r] - mm);
        const float a1 = __expf(m1 - mm);
        const float inv = 1.f / (lr[i][r] * a0 + l1 * a1);
        const int q = qbase + i * 16 + l4 * 4 + r;
        #pragma unroll
        for (int jd = 0; jd < 4; ++jd) {
          const unsigned int u = p[16 + (i * 4 + jd) * 2 + (r >> 1)];
          const float o1 = b2f((r & 1) ? (u >> 16) : (u & 0xffffu));
          const float val = (o[i][jd][r] * a0 + o1 * a1) * inv;
          Ao[(size_t)(b * 2048 + q) * 1024 + h * 64 + jd * 16 + l15] = __float2bfloat16(val);
        }
      }
  }
}

extern "C" void kernel_launch(void* const* d_in, const int* in_sizes, int n_in,
                              void* d_out, int out_size, void* d_ws, size_t ws_size,
                              hipStream_t stream)
{
  const float* x     = (const float*)d_in[0];
  const float* W_qkv = (const float*)d_in[1];
  const float* b_qkv = (const float*)d_in[2];
  const float* W_fc  = (const float*)d_in[3];
  const float* b_fc  = (const float*)d_in[4];
  float* out = (float*)d_out;

  char* ws = (char*)d_ws;
  bf16* x_bf = (bf16*)ws;  ws += (size_t)8192 * 1024 * 2;            // 16 MB
  bf16* Wqt  = (bf16*)ws;  ws += (size_t)3072 * 1024 * 2;            //  6 MB
  bf16* Wft  = (bf16*)ws;  ws += (size_t)1024 * 1024 * 2;            //  2 MB
  bf16* Qh   = (bf16*)ws;  ws += (size_t)4 * 16 * 2048 * 64 * 2;     // 16 MB
  bf16* Kh   = (bf16*)ws;  ws += (size_t)4 * 16 * 2048 * 64 * 2;     // 16 MB
  bf16* Vt   = (bf16*)ws;  ws += (size_t)4 * 16 * 64 * 2048 * 2;     // 16 MB
  bf16* Ao   = (bf16*)ws;  ws += (size_t)8192 * 1024 * 2;            // 16 MB  (total 88 MB)

  k_convert<<<8192, 256, 0, stream>>>(x, (unsigned short*)x_bf, 8192 * 1024 / 4);
  k_transpose<<<dim3(3072 / 32, 1024 / 32), dim3(32, 8), 0, stream>>>(W_qkv, Wqt, 1024, 3072);
  k_transpose<<<dim3(1024 / 32, 1024 / 32), dim3(32, 8), 0, stream>>>(W_fc, Wft, 1024, 1024);
  k_gemm<0><<<dim3(24, 64), 256, 0, stream>>>(x_bf, Wqt, b_qkv, Qh, Kh, Vt, nullptr);
  k_attn<<<2048, 256, 0, stream>>>(Qh, Kh, Vt, Ao);
  k_gemm<1><<<dim3(8, 64), 256, 0, stream>>>(Ao, Wft, b_fc, nullptr, nullptr, nullptr, out);
}

// Round 6
// 356.347 us; speedup vs baseline: 2.2872x; 1.0959x over previous
//
#include <hip/hip_runtime.h>
#include <hip/hip_bf16.h>

typedef __hip_bfloat16 bf16;
typedef short bf16x8 __attribute__((ext_vector_type(8)));
typedef float f32x4 __attribute__((ext_vector_type(4)));

// B=4, T=2048, D=1024, H=16, HD=64

static __device__ __forceinline__ void glds16(const bf16* g, bf16* l) {
  __builtin_amdgcn_global_load_lds(
      (const __attribute__((address_space(1))) void*)g,
      (__attribute__((address_space(3))) void*)l, 16, 0, 0);
}

static __device__ __forceinline__ unsigned short f2b(float f) {
  return __builtin_bit_cast(unsigned short, __float2bfloat16(f));
}
static __device__ __forceinline__ float b2f(unsigned int u16bits) {
  return __builtin_bit_cast(float, u16bits << 16);
}

// ---------------- fp32 -> bf16 convert, 4 elems/thread ----------------
__global__ void k_convert(const float* __restrict__ in, unsigned short* __restrict__ out, int n4) {
  int i = blockIdx.x * 256 + threadIdx.x;
  if (i >= n4) return;
  float4 v = reinterpret_cast<const float4*>(in)[i];
  ushort4 o;
  o.x = f2b(v.x); o.y = f2b(v.y); o.z = f2b(v.z); o.w = f2b(v.w);
  reinterpret_cast<ushort4*>(out)[i] = o;
}

// ---------------- transpose R x C fp32  ->  C x R bf16 ----------------
__global__ void k_transpose(const float* __restrict__ in, bf16* __restrict__ out, int R, int C) {
  __shared__ float t[32][33];
  int c0 = blockIdx.x * 32, r0 = blockIdx.y * 32;
  int tx = threadIdx.x, ty = threadIdx.y;  // block (32,8)
  #pragma unroll
  for (int j = 0; j < 32; j += 8)
    t[ty + j][tx] = in[(size_t)(r0 + ty + j) * C + c0 + tx];
  __syncthreads();
  #pragma unroll
  for (int j = 0; j < 32; j += 8)
    out[(size_t)(c0 + ty + j) * R + r0 + tx] = __float2bfloat16(t[tx][ty + j]);
}

// ---------------- GEMM: C = A(M x 1024) * Bt(N x 1024)^T + bias ----------------
// EPI 0: scatter to Qh/Kh[b][h][t][d], Vt[b][h][d][t] (bf16, +b_qkv)
// EPI 1: Out fp32 [m][1024] (+b_fc)
template<int EPI>
__global__ __launch_bounds__(256, 2)
void k_gemm(const bf16* __restrict__ A, const bf16* __restrict__ Bt,
            const float* __restrict__ bias,
            bf16* __restrict__ Qh, bf16* __restrict__ Kh, bf16* __restrict__ Vt,
            float* __restrict__ Out)
{
  constexpr int K = 1024;
  __shared__ bf16 sA[128 * 32];
  __shared__ bf16 sB[128 * 32];
  const int tid = threadIdx.x;
  const int wv = tid >> 6, lane = tid & 63;
  const int wr = wv >> 1, wc = wv & 1;
  const int l4 = lane >> 4, l15 = lane & 15;

  // XCD-aware bijective swizzle (nwg % 8 == 0 for both grids: 1536, 512)
  const int nbx = gridDim.x;
  const int nwg = nbx * gridDim.y;
  const int flat = blockIdx.y * nbx + blockIdx.x;
  const int cpx = nwg >> 3;
  const int swz = (flat & 7) * cpx + (flat >> 3);
  const int bx = swz % nbx;
  const int by = swz / nbx;

  const int srow = lane >> 2;         // 0..15
  const int scol = (lane & 3) * 8;    // element offset 0,8,16,24
  const bf16* gA0 = A  + (size_t)(by * 128 + wv * 16 + srow) * K + scol;
  const bf16* gB0 = Bt + (size_t)(bx * 128 + wv * 16 + srow) * K + scol;
  bf16* lA0 = sA + wv * 16 * 32;      // wave-uniform LDS base; HW adds lane*16B
  bf16* lB0 = sB + wv * 16 * 32;

  f32x4 acc[4][4];
  #pragma unroll
  for (int i = 0; i < 4; ++i)
    #pragma unroll
    for (int j = 0; j < 4; ++j) acc[i][j] = f32x4{0.f, 0.f, 0.f, 0.f};

  for (int kb = 0; kb < K; kb += 32) {
    glds16(gA0 + kb,                   lA0);
    glds16(gA0 + kb + (size_t)64 * K,  lA0 + 64 * 32);
    glds16(gB0 + kb,                   lB0);
    glds16(gB0 + kb + (size_t)64 * K,  lB0 + 64 * 32);
    __syncthreads();
    bf16x8 af[4], bfr[4];
    #pragma unroll
    for (int i = 0; i < 4; ++i)
      af[i] = *reinterpret_cast<const bf16x8*>(sA + (wr * 64 + i * 16 + l15) * 32 + l4 * 8);
    #pragma unroll
    for (int j = 0; j < 4; ++j)
      bfr[j] = *reinterpret_cast<const bf16x8*>(sB + (wc * 64 + j * 16 + l15) * 32 + l4 * 8);
    #pragma unroll
    for (int i = 0; i < 4; ++i)
      #pragma unroll
      for (int j = 0; j < 4; ++j)
        acc[i][j] = __builtin_amdgcn_mfma_f32_16x16x32_bf16(af[i], bfr[j], acc[i][j], 0, 0, 0);
    __syncthreads();
  }

  if (EPI == 0) {
    #pragma unroll
    for (int j = 0; j < 4; ++j) {
      const int n = bx * 128 + wc * 64 + j * 16 + l15;
      const float bj = bias[n];
      const int s = n >> 10;
      const int hh = (n >> 6) & 15;
      const int d = n & 63;
      #pragma unroll
      for (int i = 0; i < 4; ++i) {
        #pragma unroll
        for (int r = 0; r < 4; ++r) {
          const int m = by * 128 + wr * 64 + i * 16 + l4 * 4 + r;
          const int bb = m >> 11, t = m & 2047;
          const bf16 o = __float2bfloat16(acc[i][j][r] + bj);
          if (s == 0)      Qh[((size_t)((bb * 16 + hh) * 2048 + t)) * 64 + d] = o;
          else if (s == 1) Kh[((size_t)((bb * 16 + hh) * 2048 + t)) * 64 + d] = o;
          else             Vt[((size_t)((bb * 16 + hh) * 64 + d)) * 2048 + t] = o;
        }
      }
    }
  } else {
    #pragma unroll
    for (int j = 0; j < 4; ++j) {
      const int n = bx * 128 + wc * 64 + j * 16 + l15;
      const float bj = bias[n];
      #pragma unroll
      for (int i = 0; i < 4; ++i)
        #pragma unroll
        for (int r = 0; r < 4; ++r) {
          const int m = by * 128 + wr * 64 + i * 16 + l4 * 4 + r;
          Out[(size_t)m * 1024 + n] = acc[i][j][r] + bj;
        }
    }
  }
}

// ---------------- flash attention (causal), head-major inputs ----------------
// 1-D grid of 2048 blocks, 256 threads = 4 waves.
// Block handles q-tile pair (g, 63-g); each tile's kt range is split even/odd
// between 2 waves (online softmax per wave), partials merged through LDS.
// bid->(b,h) mapping pins all 32 blocks of one head to one XCD (bid&7).
// Spill control (R4/R5 lesson): true live set ~130-150 regs; a 128-reg cap
// (256,4) forces 200-300 MB of scratch traffic. (256,3) gives 168 regs; K/V
// fragments are loaded per-16-col-group right before their MFMAs to keep the
// peak live set small.
__global__ __launch_bounds__(256, 3)
void k_attn(const bf16* __restrict__ Qh, const bf16* __restrict__ Kh,
            const bf16* __restrict__ Vt, bf16* __restrict__ Ao)
{
  __shared__ unsigned int smem[4608];   // 18432 B: 4 P-tiles (32x72 bf16), aliased by 2 combine regions (64x33 u32 each)
  const int tid = threadIdx.x;
  const int wv = tid >> 6, lane = tid & 63;
  const int l4 = lane >> 4, l15 = lane & 15;

  const int bid = blockIdx.x;
  const int xcd = bid & 7;
  const int idx = bid >> 3;            // 0..255
  const int g   = idx & 31;
  const int grp = idx >> 5;            // 0..7
  const int bh  = grp * 8 + xcd;       // all g-blocks of a head share an XCD
  const int b = bh >> 4, h = bh & 15;

  const int role = (wv + bid) & 3;     // rotate roles across SIMDs
  const int qi = (role < 2) ? g : (63 - g);
  const int parity = role & 1;
  const int qbase = qi * 32;

  const bf16* Qp = Qh + (size_t)bh * 2048 * 64;
  const bf16* Kp = Kh + (size_t)bh * 2048 * 64;
  const bf16* Vp = Vt + (size_t)bh * 64 * 2048;
  bf16* Pw = (bf16*)smem + wv * (32 * 72);

  bf16x8 qa[2][2];
  #pragma unroll
  for (int i = 0; i < 2; ++i)
    #pragma unroll
    for (int kh = 0; kh < 2; ++kh)
      qa[i][kh] = *reinterpret_cast<const bf16x8*>(
          Qp + (size_t)(qbase + i * 16 + l15) * 64 + kh * 32 + l4 * 8);

  f32x4 o[2][4];
  float mr[2][4], lr[2][4];
  #pragma unroll
  for (int i = 0; i < 2; ++i) {
    #pragma unroll
    for (int jd = 0; jd < 4; ++jd) o[i][jd] = f32x4{0.f, 0.f, 0.f, 0.f};
    #pragma unroll
    for (int r = 0; r < 4; ++r) { mr[i][r] = -1e30f; lr[i][r] = 0.f; }
  }

  const int ktmax = (qbase + 31) >> 6;
  for (int kt = parity; kt <= ktmax; kt += 2) {
    const bool full = (kt * 64 + 63) <= qbase;

    f32x4 s[2][4];
    #pragma unroll
    for (int i = 0; i < 2; ++i)
      #pragma unroll
      for (int j = 0; j < 4; ++j) s[i][j] = f32x4{0.f, 0.f, 0.f, 0.f};
    // QK^T: K fragments loaded per-j (8 regs live at a time, not 32)
    #pragma unroll
    for (int j = 0; j < 4; ++j) {
      bf16x8 kb0 = *reinterpret_cast<const bf16x8*>(
          Kp + (size_t)(kt * 64 + j * 16 + l15) * 64 + l4 * 8);
      bf16x8 kb1 = *reinterpret_cast<const bf16x8*>(
          Kp + (size_t)(kt * 64 + j * 16 + l15) * 64 + 32 + l4 * 8);
      #pragma unroll
      for (int i = 0; i < 2; ++i) {
        s[i][j] = __builtin_amdgcn_mfma_f32_16x16x32_bf16(qa[i][0], kb0, s[i][j], 0, 0, 0);
        s[i][j] = __builtin_amdgcn_mfma_f32_16x16x32_bf16(qa[i][1], kb1, s[i][j], 0, 0, 0);
      }
    }

    // scale + causal mask (C-layout: row=(lane>>4)*4+r, col=lane&15)
    #pragma unroll
    for (int i = 0; i < 2; ++i)
      #pragma unroll
      for (int j = 0; j < 4; ++j)
        #pragma unroll
        for (int r = 0; r < 4; ++r) {
          float v = s[i][j][r] * 0.125f;
          if (!full) {
            const int q = qbase + i * 16 + l4 * 4 + r;
            const int kk = kt * 64 + j * 16 + l15;
            if (kk > q) v = -1e30f;
          }
          s[i][j][r] = v;
        }

    // online softmax per row (rows live in 16-lane groups) -- round-2-proven
    #pragma unroll
    for (int i = 0; i < 2; ++i)
      #pragma unroll
      for (int r = 0; r < 4; ++r) {
        float mx = fmaxf(fmaxf(s[i][0][r], s[i][1][r]), fmaxf(s[i][2][r], s[i][3][r]));
        #pragma unroll
        for (int dd = 1; dd < 16; dd <<= 1) mx = fmaxf(mx, __shfl_xor(mx, dd, 16));
        const float mn = fmaxf(mr[i][r], mx);
        const float al = __expf(mr[i][r] - mn);
        mr[i][r] = mn;
        float ps = 0.f;
        #pragma unroll
        for (int j = 0; j < 4; ++j) {
          const float p = __expf(s[i][j][r] - mn);
          ps += p;
          Pw[(i * 16 + l4 * 4 + r) * 72 + j * 16 + l15] = __float2bfloat16(p);
        }
        #pragma unroll
        for (int dd = 1; dd < 16; dd <<= 1) ps += __shfl_xor(ps, dd, 16);
        lr[i][r] = lr[i][r] * al + ps;
        #pragma unroll
        for (int jd = 0; jd < 4; ++jd) o[i][jd][r] *= al;
      }

    // PV: A-frags from P LDS (16 regs), V fragments loaded per-jd
    bf16x8 pa[2][2];
    #pragma unroll
    for (int i = 0; i < 2; ++i)
      #pragma unroll
      for (int kh = 0; kh < 2; ++kh)
        pa[i][kh] = *reinterpret_cast<const bf16x8*>(Pw + (i * 16 + l15) * 72 + kh * 32 + l4 * 8);
    #pragma unroll
    for (int jd = 0; jd < 4; ++jd) {
      bf16x8 vb0 = *reinterpret_cast<const bf16x8*>(
          Vp + (size_t)(jd * 16 + l15) * 2048 + kt * 64 + l4 * 8);
      bf16x8 vb1 = *reinterpret_cast<const bf16x8*>(
          Vp + (size_t)(jd * 16 + l15) * 2048 + kt * 64 + 32 + l4 * 8);
      #pragma unroll
      for (int i = 0; i < 2; ++i) {
        o[i][jd] = __builtin_amdgcn_mfma_f32_16x16x32_bf16(pa[i][0], vb0, o[i][jd], 0, 0, 0);
        o[i][jd] = __builtin_amdgcn_mfma_f32_16x16x32_bf16(pa[i][1], vb1, o[i][jd], 0, 0, 0);
      }
    }
  }

  // ---- merge even/odd partials through LDS (aliases dead P buffers) ----
  __syncthreads();
  unsigned int* reg0 = smem;          // 64 lanes x 33 u32 (stride 33 breaks 32-way bank conflict)
  unsigned int* reg1 = smem + 64 * 33;
  if (parity == 1) {                  // writers: roles 1 (tile g) and 3 (tile 63-g)
    unsigned int* p = ((role == 1) ? reg0 : reg1) + lane * 33;
    #pragma unroll
    for (int i = 0; i < 2; ++i)
      #pragma unroll
      for (int r = 0; r < 4; ++r) {
        p[i * 4 + r]     = __builtin_bit_cast(unsigned int, mr[i][r]);
        p[8 + i * 4 + r] = __builtin_bit_cast(unsigned int, lr[i][r]);
      }
    #pragma unroll
    for (int i = 0; i < 2; ++i)
      #pragma unroll
      for (int jd = 0; jd < 4; ++jd)
        #pragma unroll
        for (int rp = 0; rp < 2; ++rp) {
          unsigned int lo = f2b(o[i][jd][2 * rp]);
          unsigned int hi = f2b(o[i][jd][2 * rp + 1]);
          p[16 + (i * 4 + jd) * 2 + rp] = lo | (hi << 16);
        }
  }
  __syncthreads();
  if (parity == 0) {                  // readers: roles 0 and 2
    const unsigned int* p = ((role == 0) ? reg0 : reg1) + lane * 33;
    #pragma unroll
    for (int i = 0; i < 2; ++i)
      #pragma unroll
      for (int r = 0; r < 4; ++r) {
        const float m1 = __builtin_bit_cast(float, p[i * 4 + r]);
        const float l1 = __builtin_bit_cast(float, p[8 + i * 4 + r]);
        const float mm = fmaxf(mr[i][r], m1);
        const float a0 = __expf(mr[i][r] - mm);
        const float a1 = __expf(m1 - mm);
        const float inv = 1.f / (lr[i][r] * a0 + l1 * a1);
        const int q = qbase + i * 16 + l4 * 4 + r;
        #pragma unroll
        for (int jd = 0; jd < 4; ++jd) {
          const unsigned int u = p[16 + (i * 4 + jd) * 2 + (r >> 1)];
          const float o1 = b2f((r & 1) ? (u >> 16) : (u & 0xffffu));
          const float val = (o[i][jd][r] * a0 + o1 * a1) * inv;
          Ao[(size_t)(b * 2048 + q) * 1024 + h * 64 + jd * 16 + l15] = __float2bfloat16(val);
        }
      }
  }
}

extern "C" void kernel_launch(void* const* d_in, const int* in_sizes, int n_in,
                              void* d_out, int out_size, void* d_ws, size_t ws_size,
                              hipStream_t stream)
{
  const float* x     = (const float*)d_in[0];
  const float* W_qkv = (const float*)d_in[1];
  const float* b_qkv = (const float*)d_in[2];
  const float* W_fc  = (const float*)d_in[3];
  const float* b_fc  = (const float*)d_in[4];
  float* out = (float*)d_out;

  char* ws = (char*)d_ws;
  bf16* x_bf = (bf16*)ws;  ws += (size_t)8192 * 1024 * 2;            // 16 MB
  bf16* Wqt  = (bf16*)ws;  ws += (size_t)3072 * 1024 * 2;            //  6 MB
  bf16* Wft  = (bf16*)ws;  ws += (size_t)1024 * 1024 * 2;            //  2 MB
  bf16* Qh   = (bf16*)ws;  ws += (size_t)4 * 16 * 2048 * 64 * 2;     // 16 MB
  bf16* Kh   = (bf16*)ws;  ws += (size_t)4 * 16 * 2048 * 64 * 2;     // 16 MB
  bf16* Vt   = (bf16*)ws;  ws += (size_t)4 * 16 * 64 * 2048 * 2;     // 16 MB
  bf16* Ao   = (bf16*)ws;  ws += (size_t)8192 * 1024 * 2;            // 16 MB  (total 88 MB)

  k_convert<<<8192, 256, 0, stream>>>(x, (unsigned short*)x_bf, 8192 * 1024 / 4);
  k_transpose<<<dim3(3072 / 32, 1024 / 32), dim3(32, 8), 0, stream>>>(W_qkv, Wqt, 1024, 3072);
  k_transpose<<<dim3(1024 / 32, 1024 / 32), dim3(32, 8), 0, stream>>>(W_fc, Wft, 1024, 1024);
  k_gemm<0><<<dim3(24, 64), 256, 0, stream>>>(x_bf, Wqt, b_qkv, Qh, Kh, Vt, nullptr);
  k_attn<<<2048, 256, 0, stream>>>(Qh, Kh, Vt, Ao);
  k_gemm<1><<<dim3(8, 64), 256, 0, stream>>>(Ao, Wft, b_fc, nullptr, nullptr, nullptr, out);
}

// Round 8
// 339.569 us; speedup vs baseline: 2.4002x; 1.0494x over previous
//
#include <hip/hip_runtime.h>
#include <hip/hip_bf16.h>

typedef __hip_bfloat16 bf16;
typedef short bf16x8 __attribute__((ext_vector_type(8)));
typedef float f32x4 __attribute__((ext_vector_type(4)));

// B=4, T=2048, D=1024, H=16, HD=64

static __device__ __forceinline__ void glds16(const bf16* g, bf16* l) {
  __builtin_amdgcn_global_load_lds(
      (const __attribute__((address_space(1))) void*)g,
      (__attribute__((address_space(3))) void*)l, 16, 0, 0);
}

static __device__ __forceinline__ unsigned short f2b(float f) {
  return __builtin_bit_cast(unsigned short, __float2bfloat16(f));
}
static __device__ __forceinline__ float b2f(unsigned int u16bits) {
  return __builtin_bit_cast(float, u16bits << 16);
}
// 2^x via the clang builtin (lowers to v_exp_f32 with compiler-managed hazards)
static __device__ __forceinline__ float ex2(float x) {
  return __builtin_amdgcn_exp2f(x);
}

// ---------------- fp32 -> bf16 convert, 4 elems/thread ----------------
__global__ void k_convert(const float* __restrict__ in, unsigned short* __restrict__ out, int n4) {
  int i = blockIdx.x * 256 + threadIdx.x;
  if (i >= n4) return;
  float4 v = reinterpret_cast<const float4*>(in)[i];
  ushort4 o;
  o.x = f2b(v.x); o.y = f2b(v.y); o.z = f2b(v.z); o.w = f2b(v.w);
  reinterpret_cast<ushort4*>(out)[i] = o;
}

// ---------------- transpose R x C fp32  ->  C x R bf16 ----------------
__global__ void k_transpose(const float* __restrict__ in, bf16* __restrict__ out, int R, int C) {
  __shared__ float t[32][33];
  int c0 = blockIdx.x * 32, r0 = blockIdx.y * 32;
  int tx = threadIdx.x, ty = threadIdx.y;  // block (32,8)
  #pragma unroll
  for (int j = 0; j < 32; j += 8)
    t[ty + j][tx] = in[(size_t)(r0 + ty + j) * C + c0 + tx];
  __syncthreads();
  #pragma unroll
  for (int j = 0; j < 32; j += 8)
    out[(size_t)(c0 + ty + j) * R + r0 + tx] = __float2bfloat16(t[tx][ty + j]);
}

// ---------------- GEMM: C = A(M x 1024) * Bt(N x 1024)^T + bias ----------------
// EPI 0: scatter to Qh/Kh[b][h][t][d], Vt[b][h][d][t] (bf16, +b_qkv)
// EPI 1: Out fp32 [m][1024] (+b_fc)
template<int EPI>
__global__ __launch_bounds__(256, 2)
void k_gemm(const bf16* __restrict__ A, const bf16* __restrict__ Bt,
            const float* __restrict__ bias,
            bf16* __restrict__ Qh, bf16* __restrict__ Kh, bf16* __restrict__ Vt,
            float* __restrict__ Out)
{
  constexpr int K = 1024;
  __shared__ bf16 sA[128 * 32];
  __shared__ bf16 sB[128 * 32];
  const int tid = threadIdx.x;
  const int wv = tid >> 6, lane = tid & 63;
  const int wr = wv >> 1, wc = wv & 1;
  const int l4 = lane >> 4, l15 = lane & 15;

  // XCD-aware bijective swizzle (nwg % 8 == 0 for both grids: 1536, 512)
  const int nbx = gridDim.x;
  const int nwg = nbx * gridDim.y;
  const int flat = blockIdx.y * nbx + blockIdx.x;
  const int cpx = nwg >> 3;
  const int swz = (flat & 7) * cpx + (flat >> 3);
  const int bx = swz % nbx;
  const int by = swz / nbx;

  const int srow = lane >> 2;         // 0..15
  const int scol = (lane & 3) * 8;    // element offset 0,8,16,24
  const bf16* gA0 = A  + (size_t)(by * 128 + wv * 16 + srow) * K + scol;
  const bf16* gB0 = Bt + (size_t)(bx * 128 + wv * 16 + srow) * K + scol;
  bf16* lA0 = sA + wv * 16 * 32;      // wave-uniform LDS base; HW adds lane*16B
  bf16* lB0 = sB + wv * 16 * 32;

  f32x4 acc[4][4];
  #pragma unroll
  for (int i = 0; i < 4; ++i)
    #pragma unroll
    for (int j = 0; j < 4; ++j) acc[i][j] = f32x4{0.f, 0.f, 0.f, 0.f};

  for (int kb = 0; kb < K; kb += 32) {
    glds16(gA0 + kb,                   lA0);
    glds16(gA0 + kb + (size_t)64 * K,  lA0 + 64 * 32);
    glds16(gB0 + kb,                   lB0);
    glds16(gB0 + kb + (size_t)64 * K,  lB0 + 64 * 32);
    __syncthreads();
    bf16x8 af[4], bfr[4];
    #pragma unroll
    for (int i = 0; i < 4; ++i)
      af[i] = *reinterpret_cast<const bf16x8*>(sA + (wr * 64 + i * 16 + l15) * 32 + l4 * 8);
    #pragma unroll
    for (int j = 0; j < 4; ++j)
      bfr[j] = *reinterpret_cast<const bf16x8*>(sB + (wc * 64 + j * 16 + l15) * 32 + l4 * 8);
    #pragma unroll
    for (int i = 0; i < 4; ++i)
      #pragma unroll
      for (int j = 0; j < 4; ++j)
        acc[i][j] = __builtin_amdgcn_mfma_f32_16x16x32_bf16(af[i], bfr[j], acc[i][j], 0, 0, 0);
    __syncthreads();
  }

  if (EPI == 0) {
    #pragma unroll
    for (int j = 0; j < 4; ++j) {
      const int n = bx * 128 + wc * 64 + j * 16 + l15;
      const float bj = bias[n];
      const int s = n >> 10;
      const int hh = (n >> 6) & 15;
      const int d = n & 63;
      #pragma unroll
      for (int i = 0; i < 4; ++i) {
        #pragma unroll
        for (int r = 0; r < 4; ++r) {
          const int m = by * 128 + wr * 64 + i * 16 + l4 * 4 + r;
          const int bb = m >> 11, t = m & 2047;
          const bf16 o = __float2bfloat16(acc[i][j][r] + bj);
          if (s == 0)      Qh[((size_t)((bb * 16 + hh) * 2048 + t)) * 64 + d] = o;
          else if (s == 1) Kh[((size_t)((bb * 16 + hh) * 2048 + t)) * 64 + d] = o;
          else             Vt[((size_t)((bb * 16 + hh) * 64 + d)) * 2048 + t] = o;
        }
      }
    }
  } else {
    #pragma unroll
    for (int j = 0; j < 4; ++j) {
      const int n = bx * 128 + wc * 64 + j * 16 + l15;
      const float bj = bias[n];
      #pragma unroll
      for (int i = 0; i < 4; ++i)
        #pragma unroll
        for (int r = 0; r < 4; ++r) {
          const int m = by * 128 + wr * 64 + i * 16 + l4 * 4 + r;
          Out[(size_t)m * 1024 + n] = acc[i][j][r] + bj;
        }
    }
  }
}

// ---------------- flash attention (causal), head-major inputs ----------------
// 1-D grid of 2048 blocks, 256 threads = 4 waves.
// Block handles q-tile pair (g, 63-g); each tile's kt range is split even/odd
// between 2 waves (online softmax per wave), partials merged through LDS.
// bid->(b,h) mapping pins all 32 blocks of one head to one XCD (bid&7).
// Software pipeline (R6 lesson: per-j loads exposed ~2000 cyc latency/iter):
//   QK(kbf) -> issue V loads -> softmax (V latency hides under ~750cyc VALU)
//   -> issue K(kt+2) prefetch -> P LDS roundtrip + PV (K latency hides).
// (256,3) = 168-reg budget fits the pipeline's ~150-reg live set (R4/R5:
// a 128-reg cap spills catastrophically).
__global__ __launch_bounds__(256, 3)
void k_attn(const bf16* __restrict__ Qh, const bf16* __restrict__ Kh,
            const bf16* __restrict__ Vt, bf16* __restrict__ Ao)
{
  __shared__ unsigned int smem[4608];   // 18432 B: 4 P-tiles (32x72 bf16), aliased by 2 combine regions (64x33 u32)
  const int tid = threadIdx.x;
  const int wv = tid >> 6, lane = tid & 63;
  const int l4 = lane >> 4, l15 = lane & 15;

  const int bid = blockIdx.x;
  const int xcd = bid & 7;
  const int idx = bid >> 3;            // 0..255
  const int g   = idx & 31;
  const int grp = idx >> 5;            // 0..7
  const int bh  = grp * 8 + xcd;       // all g-blocks of a head share an XCD
  const int b = bh >> 4, h = bh & 15;

  const int role = (wv + bid) & 3;     // rotate roles across SIMDs
  const int qi = (role < 2) ? g : (63 - g);
  const int parity = role & 1;
  const int qbase = qi * 32;

  const bf16* Qp = Qh + (size_t)bh * 2048 * 64;
  const bf16* Kp = Kh + (size_t)bh * 2048 * 64;
  const bf16* Vp = Vt + (size_t)bh * 64 * 2048;
  bf16* Pw = (bf16*)smem + wv * (32 * 72);

  bf16x8 qa[2][2];
  #pragma unroll
  for (int i = 0; i < 2; ++i)
    #pragma unroll
    for (int kh = 0; kh < 2; ++kh)
      qa[i][kh] = *reinterpret_cast<const bf16x8*>(
          Qp + (size_t)(qbase + i * 16 + l15) * 64 + kh * 32 + l4 * 8);

  f32x4 o[2][4];
  float mr[2][4], lr[2][4];
  #pragma unroll
  for (int i = 0; i < 2; ++i) {
    #pragma unroll
    for (int jd = 0; jd < 4; ++jd) o[i][jd] = f32x4{0.f, 0.f, 0.f, 0.f};
    #pragma unroll
    for (int r = 0; r < 4; ++r) { mr[i][r] = -1e30f; lr[i][r] = 0.f; }
  }

  const int ktmax = (qbase + 31) >> 6;

  // prologue: K fragments for first kt (clamped; waves with parity>ktmax skip loop)
  const int kt0 = (parity <= ktmax) ? parity : ktmax;
  bf16x8 kbf[4][2];
  #pragma unroll
  for (int j = 0; j < 4; ++j)
    #pragma unroll
    for (int kh = 0; kh < 2; ++kh)
      kbf[j][kh] = *reinterpret_cast<const bf16x8*>(
          Kp + (size_t)(kt0 * 64 + j * 16 + l15) * 64 + kh * 32 + l4 * 8);

  for (int kt = parity; kt <= ktmax; kt += 2) {
    const bool full = (kt * 64 + 63) <= qbase;

    // QK^T (K fragments already resident from prologue/prefetch)
    f32x4 s[2][4];
    #pragma unroll
    for (int i = 0; i < 2; ++i)
      #pragma unroll
      for (int j = 0; j < 4; ++j) s[i][j] = f32x4{0.f, 0.f, 0.f, 0.f};
    #pragma unroll
    for (int j = 0; j < 4; ++j)
      #pragma unroll
      for (int i = 0; i < 2; ++i) {
        s[i][j] = __builtin_amdgcn_mfma_f32_16x16x32_bf16(qa[i][0], kbf[j][0], s[i][j], 0, 0, 0);
        s[i][j] = __builtin_amdgcn_mfma_f32_16x16x32_bf16(qa[i][1], kbf[j][1], s[i][j], 0, 0, 0);
      }

    // V loads issued NOW: latency hides under the softmax VALU chain
    bf16x8 vbf[4][2];
    #pragma unroll
    for (int jd = 0; jd < 4; ++jd)
      #pragma unroll
      for (int kh = 0; kh < 2; ++kh)
        vbf[jd][kh] = *reinterpret_cast<const bf16x8*>(
            Vp + (size_t)(jd * 16 + l15) * 2048 + kt * 64 + kh * 32 + l4 * 8);

    // scale (log2e folded) + causal mask (C-layout: row=(lane>>4)*4+r, col=lane&15)
    #pragma unroll
    for (int i = 0; i < 2; ++i)
      #pragma unroll
      for (int j = 0; j < 4; ++j)
        #pragma unroll
        for (int r = 0; r < 4; ++r) {
          float v = s[i][j][r] * 0.18033688f;   // 0.125 * log2(e)
          if (!full) {
            const int q = qbase + i * 16 + l4 * 4 + r;
            const int kk = kt * 64 + j * 16 + l15;
            if (kk > q) v = -1e30f;
          }
          s[i][j][r] = v;
        }

    // online softmax per row (exp2 domain; rows live in 16-lane groups)
    #pragma unroll
    for (int i = 0; i < 2; ++i)
      #pragma unroll
      for (int r = 0; r < 4; ++r) {
        float mx = fmaxf(fmaxf(s[i][0][r], s[i][1][r]), fmaxf(s[i][2][r], s[i][3][r]));
        #pragma unroll
        for (int dd = 1; dd < 16; dd <<= 1) mx = fmaxf(mx, __shfl_xor(mx, dd, 16));
        const float mn = fmaxf(mr[i][r], mx);
        const float al = ex2(mr[i][r] - mn);
        mr[i][r] = mn;
        float ps = 0.f;
        #pragma unroll
        for (int j = 0; j < 4; ++j) {
          const float p = ex2(s[i][j][r] - mn);
          ps += p;
          Pw[(i * 16 + l4 * 4 + r) * 72 + j * 16 + l15] = __float2bfloat16(p);
        }
        #pragma unroll
        for (int dd = 1; dd < 16; dd <<= 1) ps += __shfl_xor(ps, dd, 16);
        lr[i][r] = lr[i][r] * al + ps;
        #pragma unroll
        for (int jd = 0; jd < 4; ++jd) o[i][jd][r] *= al;
      }

    // K prefetch for kt+2 (clamped): latency hides under P LDS roundtrip + PV
    const int ktn = (kt + 2 <= ktmax) ? (kt + 2) : ktmax;
    #pragma unroll
    for (int j = 0; j < 4; ++j)
      #pragma unroll
      for (int kh = 0; kh < 2; ++kh)
        kbf[j][kh] = *reinterpret_cast<const bf16x8*>(
            Kp + (size_t)(ktn * 64 + j * 16 + l15) * 64 + kh * 32 + l4 * 8);

    // PV: A-frags from P LDS, B-frags from transposed V (contiguous 16B)
    bf16x8 pa[2][2];
    #pragma unroll
    for (int i = 0; i < 2; ++i)
      #pragma unroll
      for (int kh = 0; kh < 2; ++kh)
        pa[i][kh] = *reinterpret_cast<const bf16x8*>(Pw + (i * 16 + l15) * 72 + kh * 32 + l4 * 8);
    #pragma unroll
    for (int jd = 0; jd < 4; ++jd)
      #pragma unroll
      for (int i = 0; i < 2; ++i) {
        o[i][jd] = __builtin_amdgcn_mfma_f32_16x16x32_bf16(pa[i][0], vbf[jd][0], o[i][jd], 0, 0, 0);
        o[i][jd] = __builtin_amdgcn_mfma_f32_16x16x32_bf16(pa[i][1], vbf[jd][1], o[i][jd], 0, 0, 0);
      }
  }

  // ---- merge even/odd partials through LDS (aliases dead P buffers) ----
  __syncthreads();
  unsigned int* reg0 = smem;          // 64 lanes x 33 u32 (stride 33 avoids bank conflicts)
  unsigned int* reg1 = smem + 64 * 33;
  if (parity == 1) {                  // writers: roles 1 (tile g) and 3 (tile 63-g)
    unsigned int* p = ((role == 1) ? reg0 : reg1) + lane * 33;
    #pragma unroll
    for (int i = 0; i < 2; ++i)
      #pragma unroll
      for (int r = 0; r < 4; ++r) {
        p[i * 4 + r]     = __builtin_bit_cast(unsigned int, mr[i][r]);
        p[8 + i * 4 + r] = __builtin_bit_cast(unsigned int, lr[i][r]);
      }
    #pragma unroll
    for (int i = 0; i < 2; ++i)
      #pragma unroll
      for (int jd = 0; jd < 4; ++jd)
        #pragma unroll
        for (int rp = 0; rp < 2; ++rp) {
          unsigned int lo = f2b(o[i][jd][2 * rp]);
          unsigned int hi = f2b(o[i][jd][2 * rp + 1]);
          p[16 + (i * 4 + jd) * 2 + rp] = lo | (hi << 16);
        }
  }
  __syncthreads();
  if (parity == 0) {                  // readers: roles 0 and 2
    const unsigned int* p = ((role == 0) ? reg0 : reg1) + lane * 33;
    #pragma unroll
    for (int i = 0; i < 2; ++i)
      #pragma unroll
      for (int r = 0; r < 4; ++r) {
        const float m1 = __builtin_bit_cast(float, p[i * 4 + r]);
        const float l1 = __builtin_bit_cast(float, p[8 + i * 4 + r]);
        const float mm = fmaxf(mr[i][r], m1);
        const float a0 = ex2(mr[i][r] - mm);
        const float a1 = ex2(m1 - mm);
        const float inv = 1.f / (lr[i][r] * a0 + l1 * a1);
        const int q = qbase + i * 16 + l4 * 4 + r;
        #pragma unroll
        for (int jd = 0; jd < 4; ++jd) {
          const unsigned int u = p[16 + (i * 4 + jd) * 2 + (r >> 1)];
          const float o1 = b2f((r & 1) ? (u >> 16) : (u & 0xffffu));
          const float val = (o[i][jd][r] * a0 + o1 * a1) * inv;
          Ao[(size_t)(b * 2048 + q) * 1024 + h * 64 + jd * 16 + l15] = __float2bfloat16(val);
        }
      }
  }
}

extern "C" void kernel_launch(void* const* d_in, const int* in_sizes, int n_in,
                              void* d_out, int out_size, void* d_ws, size_t ws_size,
                              hipStream_t stream)
{
  const float* x     = (const float*)d_in[0];
  const float* W_qkv = (const float*)d_in[1];
  const float* b_qkv = (const float*)d_in[2];
  const float* W_fc  = (const float*)d_in[3];
  const float* b_fc  = (const float*)d_in[4];
  float* out = (float*)d_out;

  char* ws = (char*)d_ws;
  bf16* x_bf = (bf16*)ws;  ws += (size_t)8192 * 1024 * 2;            // 16 MB
  bf16* Wqt  = (bf16*)ws;  ws += (size_t)3072 * 1024 * 2;            //  6 MB
  bf16* Wft  = (bf16*)ws;  ws += (size_t)1024 * 1024 * 2;            //  2 MB
  bf16* Qh   = (bf16*)ws;  ws += (size_t)4 * 16 * 2048 * 64 * 2;     // 16 MB
  bf16* Kh   = (bf16*)ws;  ws += (size_t)4 * 16 * 2048 * 64 * 2;     // 16 MB
  bf16* Vt   = (bf16*)ws;  ws += (size_t)4 * 16 * 64 * 2048 * 2;     // 16 MB
  bf16* Ao   = (bf16*)ws;  ws += (size_t)8192 * 1024 * 2;            // 16 MB  (total 88 MB)

  k_convert<<<8192, 256, 0, stream>>>(x, (unsigned short*)x_bf, 8192 * 1024 / 4);
  k_transpose<<<dim3(3072 / 32, 1024 / 32), dim3(32, 8), 0, stream>>>(W_qkv, Wqt, 1024, 3072);
  k_transpose<<<dim3(1024 / 32, 1024 / 32), dim3(32, 8), 0, stream>>>(W_fc, Wft, 1024, 1024);
  k_gemm<0><<<dim3(24, 64), 256, 0, stream>>>(x_bf, Wqt, b_qkv, Qh, Kh, Vt, nullptr);
  k_attn<<<2048, 256, 0, stream>>>(Qh, Kh, Vt, Ao);
  k_gemm<1><<<dim3(8, 64), 256, 0, stream>>>(Ao, Wft, b_fc, nullptr, nullptr, nullptr, out);
}

// Round 9
// 285.033 us; speedup vs baseline: 2.8594x; 1.1913x over previous
//
#include <hip/hip_runtime.h>
#include <hip/hip_bf16.h>

typedef __hip_bfloat16 bf16;
typedef short bf16x8 __attribute__((ext_vector_type(8)));
typedef float f32x4 __attribute__((ext_vector_type(4)));

// B=4, T=2048, D=1024, H=16, HD=64

static __device__ __forceinline__ void glds16(const bf16* g, bf16* l) {
  __builtin_amdgcn_global_load_lds(
      (const __attribute__((address_space(1))) void*)g,
      (__attribute__((address_space(3))) void*)l, 16, 0, 0);
}

static __device__ __forceinline__ unsigned short f2b(float f) {
  return __builtin_bit_cast(unsigned short, __float2bfloat16(f));
}
static __device__ __forceinline__ float b2f(unsigned int u16bits) {
  return __builtin_bit_cast(float, u16bits << 16);
}
// 2^x via the clang builtin (lowers to v_exp_f32 with compiler-managed hazards)
static __device__ __forceinline__ float ex2(float x) {
  return __builtin_amdgcn_exp2f(x);
}

// ---------------- fp32 -> bf16 convert, 4 elems/thread ----------------
__global__ void k_convert(const float* __restrict__ in, unsigned short* __restrict__ out, int n4) {
  int i = blockIdx.x * 256 + threadIdx.x;
  if (i >= n4) return;
  float4 v = reinterpret_cast<const float4*>(in)[i];
  ushort4 o;
  o.x = f2b(v.x); o.y = f2b(v.y); o.z = f2b(v.z); o.w = f2b(v.w);
  reinterpret_cast<ushort4*>(out)[i] = o;
}

// ---------------- transpose R x C fp32  ->  C x R bf16 ----------------
__global__ void k_transpose(const float* __restrict__ in, bf16* __restrict__ out, int R, int C) {
  __shared__ float t[32][33];
  int c0 = blockIdx.x * 32, r0 = blockIdx.y * 32;
  int tx = threadIdx.x, ty = threadIdx.y;  // block (32,8)
  #pragma unroll
  for (int j = 0; j < 32; j += 8)
    t[ty + j][tx] = in[(size_t)(r0 + ty + j) * C + c0 + tx];
  __syncthreads();
  #pragma unroll
  for (int j = 0; j < 32; j += 8)
    out[(size_t)(c0 + ty + j) * R + r0 + tx] = __float2bfloat16(t[tx][ty + j]);
}

// ---------------- GEMM: C = A(M x 1024) * Bt(N x 1024)^T + bias ----------------
// EPI 0: scatter to Qh/Kh[b][h][t][d], Vt[b][h][d][t] (bf16, +b_qkv)
// EPI 1: Out fp32 [m][1024] (+b_fc)
template<int EPI>
__global__ __launch_bounds__(256, 2)
void k_gemm(const bf16* __restrict__ A, const bf16* __restrict__ Bt,
            const float* __restrict__ bias,
            bf16* __restrict__ Qh, bf16* __restrict__ Kh, bf16* __restrict__ Vt,
            float* __restrict__ Out)
{
  constexpr int K = 1024;
  __shared__ bf16 sA[128 * 32];
  __shared__ bf16 sB[128 * 32];
  const int tid = threadIdx.x;
  const int wv = tid >> 6, lane = tid & 63;
  const int wr = wv >> 1, wc = wv & 1;
  const int l4 = lane >> 4, l15 = lane & 15;

  // XCD-aware bijective swizzle (nwg % 8 == 0 for both grids: 1536, 512)
  const int nbx = gridDim.x;
  const int nwg = nbx * gridDim.y;
  const int flat = blockIdx.y * nbx + blockIdx.x;
  const int cpx = nwg >> 3;
  const int swz = (flat & 7) * cpx + (flat >> 3);
  const int bx = swz % nbx;
  const int by = swz / nbx;

  const int srow = lane >> 2;         // 0..15
  const int scol = (lane & 3) * 8;    // element offset 0,8,16,24
  const bf16* gA0 = A  + (size_t)(by * 128 + wv * 16 + srow) * K + scol;
  const bf16* gB0 = Bt + (size_t)(bx * 128 + wv * 16 + srow) * K + scol;
  bf16* lA0 = sA + wv * 16 * 32;      // wave-uniform LDS base; HW adds lane*16B
  bf16* lB0 = sB + wv * 16 * 32;

  f32x4 acc[4][4];
  #pragma unroll
  for (int i = 0; i < 4; ++i)
    #pragma unroll
    for (int j = 0; j < 4; ++j) acc[i][j] = f32x4{0.f, 0.f, 0.f, 0.f};

  for (int kb = 0; kb < K; kb += 32) {
    glds16(gA0 + kb,                   lA0);
    glds16(gA0 + kb + (size_t)64 * K,  lA0 + 64 * 32);
    glds16(gB0 + kb,                   lB0);
    glds16(gB0 + kb + (size_t)64 * K,  lB0 + 64 * 32);
    __syncthreads();
    bf16x8 af[4], bfr[4];
    #pragma unroll
    for (int i = 0; i < 4; ++i)
      af[i] = *reinterpret_cast<const bf16x8*>(sA + (wr * 64 + i * 16 + l15) * 32 + l4 * 8);
    #pragma unroll
    for (int j = 0; j < 4; ++j)
      bfr[j] = *reinterpret_cast<const bf16x8*>(sB + (wc * 64 + j * 16 + l15) * 32 + l4 * 8);
    #pragma unroll
    for (int i = 0; i < 4; ++i)
      #pragma unroll
      for (int j = 0; j < 4; ++j)
        acc[i][j] = __builtin_amdgcn_mfma_f32_16x16x32_bf16(af[i], bfr[j], acc[i][j], 0, 0, 0);
    __syncthreads();
  }

  if (EPI == 0) {
    #pragma unroll
    for (int j = 0; j < 4; ++j) {
      const int n = bx * 128 + wc * 64 + j * 16 + l15;
      const float bj = bias[n];
      const int s = n >> 10;
      const int hh = (n >> 6) & 15;
      const int d = n & 63;
      #pragma unroll
      for (int i = 0; i < 4; ++i) {
        #pragma unroll
        for (int r = 0; r < 4; ++r) {
          const int m = by * 128 + wr * 64 + i * 16 + l4 * 4 + r;
          const int bb = m >> 11, t = m & 2047;
          const bf16 o = __float2bfloat16(acc[i][j][r] + bj);
          if (s == 0)      Qh[((size_t)((bb * 16 + hh) * 2048 + t)) * 64 + d] = o;
          else if (s == 1) Kh[((size_t)((bb * 16 + hh) * 2048 + t)) * 64 + d] = o;
          else             Vt[((size_t)((bb * 16 + hh) * 64 + d)) * 2048 + t] = o;
        }
      }
    }
  } else {
    #pragma unroll
    for (int j = 0; j < 4; ++j) {
      const int n = bx * 128 + wc * 64 + j * 16 + l15;
      const float bj = bias[n];
      #pragma unroll
      for (int i = 0; i < 4; ++i)
        #pragma unroll
        for (int r = 0; r < 4; ++r) {
          const int m = by * 128 + wr * 64 + i * 16 + l4 * 4 + r;
          Out[(size_t)m * 1024 + n] = acc[i][j][r] + bj;
        }
    }
  }
}

// ---------------- flash attention (causal), head-major inputs ----------------
// 1-D grid of 2048 blocks, 256 threads = 4 waves.
// Block handles q-tile pair (g, 63-g); each tile's kt range is split even/odd
// between 2 waves (online softmax per wave), partials merged through LDS.
// bid->(b,h) mapping pins all 32 blocks of one head to one XCD (bid&7).
// SWAPPED QK^T (R8 lesson): compute S^T = mfma(K,Q) so each lane owns one
// q-row (q = l15) -> softmax is 15 local fmax + 2 shfl (was 8x8 chained
// shfl), P packs in-register to bf16 pairs -> 8 ds_write_b64 (was 32 u16).
// Rescale factor al is shuffled into O's C-layout domain (q=(l>>4)*4+r).
// (256,3): arch-reg budget ~80 is the no-spill point (R4/R5: 128-cap spills).
__global__ __launch_bounds__(256, 3)
void k_attn(const bf16* __restrict__ Qh, const bf16* __restrict__ Kh,
            const bf16* __restrict__ Vt, bf16* __restrict__ Ao)
{
  __shared__ unsigned int smem[4608];   // 18432 B: 4 P-tiles (32x72 bf16), aliased by 2 combine regions (64x33 u32)
  const int tid = threadIdx.x;
  const int wv = tid >> 6, lane = tid & 63;
  const int l4 = lane >> 4, l15 = lane & 15;

  const int bid = blockIdx.x;
  const int xcd = bid & 7;
  const int idx = bid >> 3;            // 0..255
  const int g   = idx & 31;
  const int grp = idx >> 5;            // 0..7
  const int bh  = grp * 8 + xcd;       // all g-blocks of a head share an XCD
  const int b = bh >> 4, h = bh & 15;

  const int role = (wv + bid) & 3;     // rotate roles across SIMDs
  const int qi = (role < 2) ? g : (63 - g);
  const int parity = role & 1;
  const int qbase = qi * 32;

  const bf16* Qp = Qh + (size_t)bh * 2048 * 64;
  const bf16* Kp = Kh + (size_t)bh * 2048 * 64;
  const bf16* Vp = Vt + (size_t)bh * 64 * 2048;
  bf16* Pw = (bf16*)smem + wv * (32 * 72);

  bf16x8 qa[2][2];
  #pragma unroll
  for (int i = 0; i < 2; ++i)
    #pragma unroll
    for (int kh = 0; kh < 2; ++kh)
      qa[i][kh] = *reinterpret_cast<const bf16x8*>(
          Qp + (size_t)(qbase + i * 16 + l15) * 64 + kh * 32 + l4 * 8);

  f32x4 o[2][4];
  float mr[2], lr[2];                  // per-lane: q = qbase + i*16 + l15
  #pragma unroll
  for (int i = 0; i < 2; ++i) {
    #pragma unroll
    for (int jd = 0; jd < 4; ++jd) o[i][jd] = f32x4{0.f, 0.f, 0.f, 0.f};
    mr[i] = -1e30f; lr[i] = 0.f;
  }

  const int ktmax = (qbase + 31) >> 6;

  // prologue: K fragments for first kt (clamped; waves with parity>ktmax skip loop)
  const int kt0 = (parity <= ktmax) ? parity : ktmax;
  bf16x8 kbf[4][2];
  #pragma unroll
  for (int j = 0; j < 4; ++j)
    #pragma unroll
    for (int kh = 0; kh < 2; ++kh)
      kbf[j][kh] = *reinterpret_cast<const bf16x8*>(
          Kp + (size_t)(kt0 * 64 + j * 16 + l15) * 64 + kh * 32 + l4 * 8);

  for (int kt = parity; kt <= ktmax; kt += 2) {
    const bool full = (kt * 64 + 63) <= qbase;

    // swapped QK^T: s[i][j][r] = S[q = qbase+i*16+l15][k = kt*64+j*16+l4*4+r]
    f32x4 s[2][4];
    #pragma unroll
    for (int i = 0; i < 2; ++i)
      #pragma unroll
      for (int j = 0; j < 4; ++j) s[i][j] = f32x4{0.f, 0.f, 0.f, 0.f};
    #pragma unroll
    for (int j = 0; j < 4; ++j)
      #pragma unroll
      for (int i = 0; i < 2; ++i) {
        s[i][j] = __builtin_amdgcn_mfma_f32_16x16x32_bf16(kbf[j][0], qa[i][0], s[i][j], 0, 0, 0);
        s[i][j] = __builtin_amdgcn_mfma_f32_16x16x32_bf16(kbf[j][1], qa[i][1], s[i][j], 0, 0, 0);
      }

    // V loads issued now: latency hides under the softmax VALU chain
    bf16x8 vbf[4][2];
    #pragma unroll
    for (int jd = 0; jd < 4; ++jd)
      #pragma unroll
      for (int kh = 0; kh < 2; ++kh)
        vbf[jd][kh] = *reinterpret_cast<const bf16x8*>(
            Vp + (size_t)(jd * 16 + l15) * 2048 + kt * 64 + kh * 32 + l4 * 8);

    // scale (log2e folded) + causal mask; q is lane-uniform per i
    #pragma unroll
    for (int i = 0; i < 2; ++i) {
      const int q = qbase + i * 16 + l15;
      #pragma unroll
      for (int j = 0; j < 4; ++j)
        #pragma unroll
        for (int r = 0; r < 4; ++r) {
          float v = s[i][j][r] * 0.18033688f;   // 0.125 * log2(e)
          if (!full) {
            const int kk = kt * 64 + j * 16 + l4 * 4 + r;
            if (kk > q) v = -1e30f;
          }
          s[i][j][r] = v;
        }
    }

    // lane-local softmax per i (row q = l15-group), exp2 domain
    float albc[2][4];
    #pragma unroll
    for (int i = 0; i < 2; ++i) {
      float mx = s[i][0][0];
      #pragma unroll
      for (int j = 0; j < 4; ++j)
        #pragma unroll
        for (int r = 0; r < 4; ++r)
          if (j + r > 0) mx = fmaxf(mx, s[i][j][r]);
      mx = fmaxf(mx, __shfl_xor(mx, 16));
      mx = fmaxf(mx, __shfl_xor(mx, 32));
      const float mn = fmaxf(mr[i], mx);
      const float al = ex2(mr[i] - mn);
      mr[i] = mn;
      float ps = 0.f;
      #pragma unroll
      for (int j = 0; j < 4; ++j) {
        const float p0 = ex2(s[i][j][0] - mn);
        const float p1 = ex2(s[i][j][1] - mn);
        const float p2 = ex2(s[i][j][2] - mn);
        const float p3 = ex2(s[i][j][3] - mn);
        ps += (p0 + p1) + (p2 + p3);
        const unsigned int u0 = (unsigned int)f2b(p0) | ((unsigned int)f2b(p1) << 16);
        const unsigned int u1 = (unsigned int)f2b(p2) | ((unsigned int)f2b(p3) << 16);
        *reinterpret_cast<uint2*>(Pw + (i * 16 + l15) * 72 + j * 16 + l4 * 4) =
            make_uint2(u0, u1);
      }
      ps += __shfl_xor(ps, 16);
      ps += __shfl_xor(ps, 32);
      lr[i] = lr[i] * al + ps;
      // broadcast al into O's C-layout domain (q_local = l4*4 + r)
      #pragma unroll
      for (int r = 0; r < 4; ++r) albc[i][r] = __shfl(al, l4 * 4 + r);
    }
    #pragma unroll
    for (int i = 0; i < 2; ++i)
      #pragma unroll
      for (int jd = 0; jd < 4; ++jd)
        #pragma unroll
        for (int r = 0; r < 4; ++r) o[i][jd][r] *= albc[i][r];

    // K prefetch for kt+2 (clamped)
    const int ktn = (kt + 2 <= ktmax) ? (kt + 2) : ktmax;
    #pragma unroll
    for (int j = 0; j < 4; ++j)
      #pragma unroll
      for (int kh = 0; kh < 2; ++kh)
        kbf[j][kh] = *reinterpret_cast<const bf16x8*>(
            Kp + (size_t)(ktn * 64 + j * 16 + l15) * 64 + kh * 32 + l4 * 8);

    // PV: A-frags from P LDS, B-frags from transposed V (contiguous 16B)
    bf16x8 pa[2][2];
    #pragma unroll
    for (int i = 0; i < 2; ++i)
      #pragma unroll
      for (int kh = 0; kh < 2; ++kh)
        pa[i][kh] = *reinterpret_cast<const bf16x8*>(Pw + (i * 16 + l15) * 72 + kh * 32 + l4 * 8);
    #pragma unroll
    for (int jd = 0; jd < 4; ++jd)
      #pragma unroll
      for (int i = 0; i < 2; ++i) {
        o[i][jd] = __builtin_amdgcn_mfma_f32_16x16x32_bf16(pa[i][0], vbf[jd][0], o[i][jd], 0, 0, 0);
        o[i][jd] = __builtin_amdgcn_mfma_f32_16x16x32_bf16(pa[i][1], vbf[jd][1], o[i][jd], 0, 0, 0);
      }
  }

  // convert m/l to O's C-layout domain (q_local = l4*4 + r) for the merge
  float mrv[2][4], lrv[2][4];
  #pragma unroll
  for (int i = 0; i < 2; ++i)
    #pragma unroll
    for (int r = 0; r < 4; ++r) {
      mrv[i][r] = __shfl(mr[i], l4 * 4 + r);
      lrv[i][r] = __shfl(lr[i], l4 * 4 + r);
    }

  // ---- merge even/odd partials through LDS (aliases dead P buffers) ----
  __syncthreads();
  unsigned int* reg0 = smem;          // 64 lanes x 33 u32 (stride 33 avoids bank conflicts)
  unsigned int* reg1 = smem + 64 * 33;
  if (parity == 1) {                  // writers: roles 1 (tile g) and 3 (tile 63-g)
    unsigned int* p = ((role == 1) ? reg0 : reg1) + lane * 33;
    #pragma unroll
    for (int i = 0; i < 2; ++i)
      #pragma unroll
      for (int r = 0; r < 4; ++r) {
        p[i * 4 + r]     = __builtin_bit_cast(unsigned int, mrv[i][r]);
        p[8 + i * 4 + r] = __builtin_bit_cast(unsigned int, lrv[i][r]);
      }
    #pragma unroll
    for (int i = 0; i < 2; ++i)
      #pragma unroll
      for (int jd = 0; jd < 4; ++jd)
        #pragma unroll
        for (int rp = 0; rp < 2; ++rp) {
          unsigned int lo = f2b(o[i][jd][2 * rp]);
          unsigned int hi = f2b(o[i][jd][2 * rp + 1]);
          p[16 + (i * 4 + jd) * 2 + rp] = lo | (hi << 16);
        }
  }
  __syncthreads();
  if (parity == 0) {                  // readers: roles 0 and 2
    const unsigned int* p = ((role == 0) ? reg0 : reg1) + lane * 33;
    #pragma unroll
    for (int i = 0; i < 2; ++i)
      #pragma unroll
      for (int r = 0; r < 4; ++r) {
        const float m1 = __builtin_bit_cast(float, p[i * 4 + r]);
        const float l1 = __builtin_bit_cast(float, p[8 + i * 4 + r]);
        const float mm = fmaxf(mrv[i][r], m1);
        const float a0 = ex2(mrv[i][r] - mm);
        const float a1 = ex2(m1 - mm);
        const float inv = 1.f / (lrv[i][r] * a0 + l1 * a1);
        const int q = qbase + i * 16 + l4 * 4 + r;
        #pragma unroll
        for (int jd = 0; jd < 4; ++jd) {
          const unsigned int u = p[16 + (i * 4 + jd) * 2 + (r >> 1)];
          const float o1 = b2f((r & 1) ? (u >> 16) : (u & 0xffffu));
          const float val = (o[i][jd][r] * a0 + o1 * a1) * inv;
          Ao[(size_t)(b * 2048 + q) * 1024 + h * 64 + jd * 16 + l15] = __float2bfloat16(val);
        }
      }
  }
}

extern "C" void kernel_launch(void* const* d_in, const int* in_sizes, int n_in,
                              void* d_out, int out_size, void* d_ws, size_t ws_size,
                              hipStream_t stream)
{
  const float* x     = (const float*)d_in[0];
  const float* W_qkv = (const float*)d_in[1];
  const float* b_qkv = (const float*)d_in[2];
  const float* W_fc  = (const float*)d_in[3];
  const float* b_fc  = (const float*)d_in[4];
  float* out = (float*)d_out;

  char* ws = (char*)d_ws;
  bf16* x_bf = (bf16*)ws;  ws += (size_t)8192 * 1024 * 2;            // 16 MB
  bf16* Wqt  = (bf16*)ws;  ws += (size_t)3072 * 1024 * 2;            //  6 MB
  bf16* Wft  = (bf16*)ws;  ws += (size_t)1024 * 1024 * 2;            //  2 MB
  bf16* Qh   = (bf16*)ws;  ws += (size_t)4 * 16 * 2048 * 64 * 2;     // 16 MB
  bf16* Kh   = (bf16*)ws;  ws += (size_t)4 * 16 * 2048 * 64 * 2;     // 16 MB
  bf16* Vt   = (bf16*)ws;  ws += (size_t)4 * 16 * 64 * 2048 * 2;     // 16 MB
  bf16* Ao   = (bf16*)ws;  ws += (size_t)8192 * 1024 * 2;            // 16 MB  (total 88 MB)

  k_convert<<<8192, 256, 0, stream>>>(x, (unsigned short*)x_bf, 8192 * 1024 / 4);
  k_transpose<<<dim3(3072 / 32, 1024 / 32), dim3(32, 8), 0, stream>>>(W_qkv, Wqt, 1024, 3072);
  k_transpose<<<dim3(1024 / 32, 1024 / 32), dim3(32, 8), 0, stream>>>(W_fc, Wft, 1024, 1024);
  k_gemm<0><<<dim3(24, 64), 256, 0, stream>>>(x_bf, Wqt, b_qkv, Qh, Kh, Vt, nullptr);
  k_attn<<<2048, 256, 0, stream>>>(Qh, Kh, Vt, Ao);
  k_gemm<1><<<dim3(8, 64), 256, 0, stream>>>(Ao, Wft, b_fc, nullptr, nullptr, nullptr, out);
}

// Round 10
// 272.903 us; speedup vs baseline: 2.9865x; 1.0444x over previous
//
#include <hip/hip_runtime.h>
#include <hip/hip_bf16.h>

typedef __hip_bfloat16 bf16;
typedef short bf16x8 __attribute__((ext_vector_type(8)));
typedef float f32x4 __attribute__((ext_vector_type(4)));

// B=4, T=2048, D=1024, H=16, HD=64

static __device__ __forceinline__ void glds16(const bf16* g, bf16* l) {
  __builtin_amdgcn_global_load_lds(
      (const __attribute__((address_space(1))) void*)g,
      (__attribute__((address_space(3))) void*)l, 16, 0, 0);
}

static __device__ __forceinline__ unsigned short f2b(float f) {
  return __builtin_bit_cast(unsigned short, __float2bfloat16(f));
}
static __device__ __forceinline__ float b2f(unsigned int u16bits) {
  return __builtin_bit_cast(float, u16bits << 16);
}
// 2^x via the clang builtin (lowers to v_exp_f32 with compiler-managed hazards)
static __device__ __forceinline__ float ex2(float x) {
  return __builtin_amdgcn_exp2f(x);
}

// ---------------- fp32 -> bf16 convert, 4 elems/thread ----------------
__global__ void k_convert(const float* __restrict__ in, unsigned short* __restrict__ out, int n4) {
  int i = blockIdx.x * 256 + threadIdx.x;
  if (i >= n4) return;
  float4 v = reinterpret_cast<const float4*>(in)[i];
  ushort4 o;
  o.x = f2b(v.x); o.y = f2b(v.y); o.z = f2b(v.z); o.w = f2b(v.w);
  reinterpret_cast<ushort4*>(out)[i] = o;
}

// ---------------- transpose R x C fp32  ->  C x R bf16 ----------------
__global__ void k_transpose(const float* __restrict__ in, bf16* __restrict__ out, int R, int C) {
  __shared__ float t[32][33];
  int c0 = blockIdx.x * 32, r0 = blockIdx.y * 32;
  int tx = threadIdx.x, ty = threadIdx.y;  // block (32,8)
  #pragma unroll
  for (int j = 0; j < 32; j += 8)
    t[ty + j][tx] = in[(size_t)(r0 + ty + j) * C + c0 + tx];
  __syncthreads();
  #pragma unroll
  for (int j = 0; j < 32; j += 8)
    out[(size_t)(c0 + ty + j) * R + r0 + tx] = __float2bfloat16(t[tx][ty + j]);
}

// ---------------- GEMM: C = A(M x 1024) * Bt(N x 1024)^T + bias ----------------
// EPI 0: scatter to Qh/Kh[b][h][t][d], Vt[b][h][d][t] (bf16, +b_qkv)
// EPI 1: Out fp32 [m][1024] (+b_fc)
template<int EPI>
__global__ __launch_bounds__(256, 2)
void k_gemm(const bf16* __restrict__ A, const bf16* __restrict__ Bt,
            const float* __restrict__ bias,
            bf16* __restrict__ Qh, bf16* __restrict__ Kh, bf16* __restrict__ Vt,
            float* __restrict__ Out)
{
  constexpr int K = 1024;
  __shared__ bf16 sA[128 * 32];
  __shared__ bf16 sB[128 * 32];
  const int tid = threadIdx.x;
  const int wv = tid >> 6, lane = tid & 63;
  const int wr = wv >> 1, wc = wv & 1;
  const int l4 = lane >> 4, l15 = lane & 15;

  // XCD-aware bijective swizzle (nwg % 8 == 0 for both grids: 1536, 512)
  const int nbx = gridDim.x;
  const int nwg = nbx * gridDim.y;
  const int flat = blockIdx.y * nbx + blockIdx.x;
  const int cpx = nwg >> 3;
  const int swz = (flat & 7) * cpx + (flat >> 3);
  const int bx = swz % nbx;
  const int by = swz / nbx;

  const int srow = lane >> 2;         // 0..15
  const int scol = (lane & 3) * 8;    // element offset 0,8,16,24
  const bf16* gA0 = A  + (size_t)(by * 128 + wv * 16 + srow) * K + scol;
  const bf16* gB0 = Bt + (size_t)(bx * 128 + wv * 16 + srow) * K + scol;
  bf16* lA0 = sA + wv * 16 * 32;      // wave-uniform LDS base; HW adds lane*16B
  bf16* lB0 = sB + wv * 16 * 32;

  f32x4 acc[4][4];
  #pragma unroll
  for (int i = 0; i < 4; ++i)
    #pragma unroll
    for (int j = 0; j < 4; ++j) acc[i][j] = f32x4{0.f, 0.f, 0.f, 0.f};

  for (int kb = 0; kb < K; kb += 32) {
    glds16(gA0 + kb,                   lA0);
    glds16(gA0 + kb + (size_t)64 * K,  lA0 + 64 * 32);
    glds16(gB0 + kb,                   lB0);
    glds16(gB0 + kb + (size_t)64 * K,  lB0 + 64 * 32);
    __syncthreads();
    bf16x8 af[4], bfr[4];
    #pragma unroll
    for (int i = 0; i < 4; ++i)
      af[i] = *reinterpret_cast<const bf16x8*>(sA + (wr * 64 + i * 16 + l15) * 32 + l4 * 8);
    #pragma unroll
    for (int j = 0; j < 4; ++j)
      bfr[j] = *reinterpret_cast<const bf16x8*>(sB + (wc * 64 + j * 16 + l15) * 32 + l4 * 8);
    #pragma unroll
    for (int i = 0; i < 4; ++i)
      #pragma unroll
      for (int j = 0; j < 4; ++j)
        acc[i][j] = __builtin_amdgcn_mfma_f32_16x16x32_bf16(af[i], bfr[j], acc[i][j], 0, 0, 0);
    __syncthreads();
  }

  if (EPI == 0) {
    #pragma unroll
    for (int j = 0; j < 4; ++j) {
      const int n = bx * 128 + wc * 64 + j * 16 + l15;
      const float bj = bias[n];
      const int s = n >> 10;
      const int hh = (n >> 6) & 15;
      const int d = n & 63;
      #pragma unroll
      for (int i = 0; i < 4; ++i) {
        #pragma unroll
        for (int r = 0; r < 4; ++r) {
          const int m = by * 128 + wr * 64 + i * 16 + l4 * 4 + r;
          const int bb = m >> 11, t = m & 2047;
          const bf16 o = __float2bfloat16(acc[i][j][r] + bj);
          if (s == 0)      Qh[((size_t)((bb * 16 + hh) * 2048 + t)) * 64 + d] = o;
          else if (s == 1) Kh[((size_t)((bb * 16 + hh) * 2048 + t)) * 64 + d] = o;
          else             Vt[((size_t)((bb * 16 + hh) * 64 + d)) * 2048 + t] = o;
        }
      }
    }
  } else {
    #pragma unroll
    for (int j = 0; j < 4; ++j) {
      const int n = bx * 128 + wc * 64 + j * 16 + l15;
      const float bj = bias[n];
      #pragma unroll
      for (int i = 0; i < 4; ++i)
        #pragma unroll
        for (int r = 0; r < 4; ++r) {
          const int m = by * 128 + wr * 64 + i * 16 + l4 * 4 + r;
          Out[(size_t)m * 1024 + n] = acc[i][j][r] + bj;
        }
    }
  }
}

// ---------------- flash attention (causal), head-major inputs ----------------
// 1-D grid of 2048 blocks, 256 threads = 4 waves.
// Block handles q-tile pair (g, 63-g); each tile's kt range is split even/odd
// between 2 waves (online softmax per wave), partials merged through LDS.
// bid->(b,h) mapping pins all 32 blocks of one head to one XCD (bid&7).
// KT=32 (R9 lesson): VGPR_Count=84 arch + ~64 accum ~= 148 total -> >128
// occupancy bucket -> only 2.2 waves/SIMD resident, latency exposed. Halving
// the K-tile halves kbf/vbf/s (-48 regs) -> total ~100-115 <= 128 -> 4
// waves/SIMD. Defer-max (THR=8, exp2 domain): skip O-rescale when the tile
// max doesn't grow past mr+8 (P bounded by 2^8; fp32 accum absorbs it).
__global__ __launch_bounds__(256, 3)
void k_attn(const bf16* __restrict__ Qh, const bf16* __restrict__ Kh,
            const bf16* __restrict__ Vt, bf16* __restrict__ Ao)
{
  __shared__ unsigned int smem[4608];   // 18432 B: 4 P-tiles (32x40 bf16) aliased by 2 combine regions (64x33 u32)
  const int tid = threadIdx.x;
  const int wv = tid >> 6, lane = tid & 63;
  const int l4 = lane >> 4, l15 = lane & 15;

  const int bid = blockIdx.x;
  const int xcd = bid & 7;
  const int idx = bid >> 3;            // 0..255
  const int g   = idx & 31;
  const int grp = idx >> 5;            // 0..7
  const int bh  = grp * 8 + xcd;       // all g-blocks of a head share an XCD
  const int b = bh >> 4, h = bh & 15;

  const int role = (wv + bid) & 3;     // rotate roles across SIMDs
  const int qi = (role < 2) ? g : (63 - g);
  const int parity = role & 1;
  const int qbase = qi * 32;

  const bf16* Qp = Qh + (size_t)bh * 2048 * 64;
  const bf16* Kp = Kh + (size_t)bh * 2048 * 64;
  const bf16* Vp = Vt + (size_t)bh * 64 * 2048;
  bf16* Pw = (bf16*)smem + wv * (32 * 40);

  bf16x8 qa[2][2];
  #pragma unroll
  for (int i = 0; i < 2; ++i)
    #pragma unroll
    for (int kh = 0; kh < 2; ++kh)
      qa[i][kh] = *reinterpret_cast<const bf16x8*>(
          Qp + (size_t)(qbase + i * 16 + l15) * 64 + kh * 32 + l4 * 8);

  f32x4 o[2][4];
  float mr[2], lr[2];                  // per-lane: q = qbase + i*16 + l15
  #pragma unroll
  for (int i = 0; i < 2; ++i) {
    #pragma unroll
    for (int jd = 0; jd < 4; ++jd) o[i][jd] = f32x4{0.f, 0.f, 0.f, 0.f};
    mr[i] = -1e30f; lr[i] = 0.f;
  }

  const int ktmax = (qbase + 31) >> 5;   // KT=32 granularity

  // prologue: K fragments for first kt (clamped; waves with parity>ktmax skip loop)
  const int kt0 = (parity <= ktmax) ? parity : ktmax;
  bf16x8 kbf[2][2];
  #pragma unroll
  for (int j = 0; j < 2; ++j)
    #pragma unroll
    for (int kh = 0; kh < 2; ++kh)
      kbf[j][kh] = *reinterpret_cast<const bf16x8*>(
          Kp + (size_t)(kt0 * 32 + j * 16 + l15) * 64 + kh * 32 + l4 * 8);

  for (int kt = parity; kt <= ktmax; kt += 2) {
    const bool full = (kt * 32 + 31) <= qbase;

    // swapped QK^T: s[i][j][r] = S[q = qbase+i*16+l15][k = kt*32+j*16+l4*4+r]
    f32x4 s[2][2];
    #pragma unroll
    for (int i = 0; i < 2; ++i)
      #pragma unroll
      for (int j = 0; j < 2; ++j) s[i][j] = f32x4{0.f, 0.f, 0.f, 0.f};
    #pragma unroll
    for (int j = 0; j < 2; ++j)
      #pragma unroll
      for (int i = 0; i < 2; ++i) {
        s[i][j] = __builtin_amdgcn_mfma_f32_16x16x32_bf16(kbf[j][0], qa[i][0], s[i][j], 0, 0, 0);
        s[i][j] = __builtin_amdgcn_mfma_f32_16x16x32_bf16(kbf[j][1], qa[i][1], s[i][j], 0, 0, 0);
      }

    // V loads issued now: latency hides under the softmax VALU chain (KT=32 -> single kh)
    bf16x8 vbf[4];
    #pragma unroll
    for (int jd = 0; jd < 4; ++jd)
      vbf[jd] = *reinterpret_cast<const bf16x8*>(
          Vp + (size_t)(jd * 16 + l15) * 2048 + kt * 32 + l4 * 8);

    // scale (log2e folded) + causal mask; q is lane-uniform per i
    #pragma unroll
    for (int i = 0; i < 2; ++i) {
      const int q = qbase + i * 16 + l15;
      #pragma unroll
      for (int j = 0; j < 2; ++j)
        #pragma unroll
        for (int r = 0; r < 4; ++r) {
          float v = s[i][j][r] * 0.18033688f;   // 0.125 * log2(e)
          if (!full) {
            const int kk = kt * 32 + j * 16 + l4 * 4 + r;
            if (kk > q) v = -1e30f;
          }
          s[i][j][r] = v;
        }
    }

    // lane-local softmax per i (row q), exp2 domain, defer-max THR=8
    #pragma unroll
    for (int i = 0; i < 2; ++i) {
      float mx = s[i][0][0];
      #pragma unroll
      for (int j = 0; j < 2; ++j)
        #pragma unroll
        for (int r = 0; r < 4; ++r)
          if (j + r > 0) mx = fmaxf(mx, s[i][j][r]);
      mx = fmaxf(mx, __shfl_xor(mx, 16));
      mx = fmaxf(mx, __shfl_xor(mx, 32));
      if (__any(mx > mr[i] + 8.f)) {        // rescale only when max grows materially
        const float mn = fmaxf(mr[i], mx);
        const float al = ex2(mr[i] - mn);
        mr[i] = mn;
        lr[i] *= al;
        float albc[4];
        #pragma unroll
        for (int r = 0; r < 4; ++r) albc[r] = __shfl(al, l4 * 4 + r);
        #pragma unroll
        for (int jd = 0; jd < 4; ++jd)
          #pragma unroll
          for (int r = 0; r < 4; ++r) o[i][jd][r] *= albc[r];
      }
      float ps = 0.f;
      #pragma unroll
      for (int j = 0; j < 2; ++j) {
        const float p0 = ex2(s[i][j][0] - mr[i]);
        const float p1 = ex2(s[i][j][1] - mr[i]);
        const float p2 = ex2(s[i][j][2] - mr[i]);
        const float p3 = ex2(s[i][j][3] - mr[i]);
        ps += (p0 + p1) + (p2 + p3);
        const unsigned int u0 = (unsigned int)f2b(p0) | ((unsigned int)f2b(p1) << 16);
        const unsigned int u1 = (unsigned int)f2b(p2) | ((unsigned int)f2b(p3) << 16);
        *reinterpret_cast<uint2*>(Pw + (i * 16 + l15) * 40 + j * 16 + l4 * 4) =
            make_uint2(u0, u1);
      }
      ps += __shfl_xor(ps, 16);
      ps += __shfl_xor(ps, 32);
      lr[i] += ps;
    }

    // K prefetch for kt+2 (clamped)
    const int ktn = (kt + 2 <= ktmax) ? (kt + 2) : ktmax;
    #pragma unroll
    for (int j = 0; j < 2; ++j)
      #pragma unroll
      for (int kh = 0; kh < 2; ++kh)
        kbf[j][kh] = *reinterpret_cast<const bf16x8*>(
            Kp + (size_t)(ktn * 32 + j * 16 + l15) * 64 + kh * 32 + l4 * 8);

    // PV: A-frags from P LDS (single kh at KT=32), B-frags from transposed V
    bf16x8 pa[2];
    #pragma unroll
    for (int i = 0; i < 2; ++i)
      pa[i] = *reinterpret_cast<const bf16x8*>(Pw + (i * 16 + l15) * 40 + l4 * 8);
    #pragma unroll
    for (int jd = 0; jd < 4; ++jd)
      #pragma unroll
      for (int i = 0; i < 2; ++i)
        o[i][jd] = __builtin_amdgcn_mfma_f32_16x16x32_bf16(pa[i], vbf[jd], o[i][jd], 0, 0, 0);
  }

  // convert m/l to O's C-layout domain (q_local = l4*4 + r) for the merge
  float mrv[2][4], lrv[2][4];
  #pragma unroll
  for (int i = 0; i < 2; ++i)
    #pragma unroll
    for (int r = 0; r < 4; ++r) {
      mrv[i][r] = __shfl(mr[i], l4 * 4 + r);
      lrv[i][r] = __shfl(lr[i], l4 * 4 + r);
    }

  // ---- merge even/odd partials through LDS (aliases dead P buffers) ----
  __syncthreads();
  unsigned int* reg0 = smem;          // 64 lanes x 33 u32 (stride 33 avoids bank conflicts)
  unsigned int* reg1 = smem + 64 * 33;
  if (parity == 1) {                  // writers: roles 1 (tile g) and 3 (tile 63-g)
    unsigned int* p = ((role == 1) ? reg0 : reg1) + lane * 33;
    #pragma unroll
    for (int i = 0; i < 2; ++i)
      #pragma unroll
      for (int r = 0; r < 4; ++r) {
        p[i * 4 + r]     = __builtin_bit_cast(unsigned int, mrv[i][r]);
        p[8 + i * 4 + r] = __builtin_bit_cast(unsigned int, lrv[i][r]);
      }
    #pragma unroll
    for (int i = 0; i < 2; ++i)
      #pragma unroll
      for (int jd = 0; jd < 4; ++jd)
        #pragma unroll
        for (int rp = 0; rp < 2; ++rp) {
          unsigned int lo = f2b(o[i][jd][2 * rp]);
          unsigned int hi = f2b(o[i][jd][2 * rp + 1]);
          p[16 + (i * 4 + jd) * 2 + rp] = lo | (hi << 16);
        }
  }
  __syncthreads();
  if (parity == 0) {                  // readers: roles 0 and 2
    const unsigned int* p = ((role == 0) ? reg0 : reg1) + lane * 33;
    #pragma unroll
    for (int i = 0; i < 2; ++i)
      #pragma unroll
      for (int r = 0; r < 4; ++r) {
        const float m1 = __builtin_bit_cast(float, p[i * 4 + r]);
        const float l1 = __builtin_bit_cast(float, p[8 + i * 4 + r]);
        const float mm = fmaxf(mrv[i][r], m1);
        const float a0 = ex2(mrv[i][r] - mm);
        const float a1 = ex2(m1 - mm);
        const float inv = 1.f / (lrv[i][r] * a0 + l1 * a1);
        const int q = qbase + i * 16 + l4 * 4 + r;
        #pragma unroll
        for (int jd = 0; jd < 4; ++jd) {
          const unsigned int u = p[16 + (i * 4 + jd) * 2 + (r >> 1)];
          const float o1 = b2f((r & 1) ? (u >> 16) : (u & 0xffffu));
          const float val = (o[i][jd][r] * a0 + o1 * a1) * inv;
          Ao[(size_t)(b * 2048 + q) * 1024 + h * 64 + jd * 16 + l15] = __float2bfloat16(val);
        }
      }
  }
}

extern "C" void kernel_launch(void* const* d_in, const int* in_sizes, int n_in,
                              void* d_out, int out_size, void* d_ws, size_t ws_size,
                              hipStream_t stream)
{
  const float* x     = (const float*)d_in[0];
  const float* W_qkv = (const float*)d_in[1];
  const float* b_qkv = (const float*)d_in[2];
  const float* W_fc  = (const float*)d_in[3];
  const float* b_fc  = (const float*)d_in[4];
  float* out = (float*)d_out;

  char* ws = (char*)d_ws;
  bf16* x_bf = (bf16*)ws;  ws += (size_t)8192 * 1024 * 2;            // 16 MB
  bf16* Wqt  = (bf16*)ws;  ws += (size_t)3072 * 1024 * 2;            //  6 MB
  bf16* Wft  = (bf16*)ws;  ws += (size_t)1024 * 1024 * 2;            //  2 MB
  bf16* Qh   = (bf16*)ws;  ws += (size_t)4 * 16 * 2048 * 64 * 2;     // 16 MB
  bf16* Kh   = (bf16*)ws;  ws += (size_t)4 * 16 * 2048 * 64 * 2;     // 16 MB
  bf16* Vt   = (bf16*)ws;  ws += (size_t)4 * 16 * 64 * 2048 * 2;     // 16 MB
  bf16* Ao   = (bf16*)ws;  ws += (size_t)8192 * 1024 * 2;            // 16 MB  (total 88 MB)

  k_convert<<<8192, 256, 0, stream>>>(x, (unsigned short*)x_bf, 8192 * 1024 / 4);
  k_transpose<<<dim3(3072 / 32, 1024 / 32), dim3(32, 8), 0, stream>>>(W_qkv, Wqt, 1024, 3072);
  k_transpose<<<dim3(1024 / 32, 1024 / 32), dim3(32, 8), 0, stream>>>(W_fc, Wft, 1024, 1024);
  k_gemm<0><<<dim3(24, 64), 256, 0, stream>>>(x_bf, Wqt, b_qkv, Qh, Kh, Vt, nullptr);
  k_attn<<<2048, 256, 0, stream>>>(Qh, Kh, Vt, Ao);
  k_gemm<1><<<dim3(8, 64), 256, 0, stream>>>(Ao, Wft, b_fc, nullptr, nullptr, nullptr, out);
}